// Round 1
// baseline (874.132 us; speedup 1.0000x reference)
//
#include <hip/hip_runtime.h>

#define N_NODES 32768
#define G_GRAPHS 1024
#define D_DIM 512
#define H_DIM 768
#define B_BR 4
#define GHD 64
#define NHD 3

// output layout (f32, concatenated flat):
// graph_head: [0, G*GHD)
// node_head : [G*GHD, G*GHD + N*NHD)
// graph_var : [G*GHD + N*NHD, 2*G*GHD + N*NHD)
// node_var  : [2*G*GHD + N*NHD, 2*G*GHD + 2*N*NHD)
#define NH_OFF (G_GRAPHS * GHD)
#define GV_OFF (G_GRAPHS * GHD + N_NODES * NHD)
#define NV_OFF (2 * G_GRAPHS * GHD + N_NODES * NHD)

// ---------------------------------------------------------------------------
// Kernel B: build per-branch node index lists
// ---------------------------------------------------------------------------
__global__ __launch_bounds__(256) void build_lists_kernel(
    const int* __restrict__ batch, const int* __restrict__ dataset_name,
    int* __restrict__ cnt, int* __restrict__ lists) {
  int n = blockIdx.x * 256 + threadIdx.x;
  if (n >= N_NODES) return;
  int b = dataset_name[batch[n]];
  int pos = atomicAdd(&cnt[b], 1);
  lists[b * N_NODES + pos] = n;
}

// ---------------------------------------------------------------------------
// Kernel A: fused graph path. One block per graph.
// pool(mean) -> relu(xg @ Wg_shared[b] + bg_shared[b]) -> @ Wg_head[b] + bg_head[b]
// ---------------------------------------------------------------------------
__global__ __launch_bounds__(256) void graph_kernel(
    const float* __restrict__ x, const int* __restrict__ batch,
    const int* __restrict__ dataset_name,
    const float* __restrict__ Wg_shared, const float* __restrict__ bg_shared,
    const float* __restrict__ Wg_head, const float* __restrict__ bg_head,
    float* __restrict__ out) {
  __shared__ float xg[D_DIM];
  __shared__ float hg[H_DIM];
  const int g = blockIdx.x;
  const int tid = threadIdx.x;

  // binary search segment bounds in sorted batch
  int lo = 0, hi = N_NODES;
  while (lo < hi) { int mid = (lo + hi) >> 1; if (batch[mid] < g) lo = mid + 1; else hi = mid; }
  const int start = lo;
  hi = N_NODES;
  while (lo < hi) { int mid = (lo + hi) >> 1; if (batch[mid] < g + 1) lo = mid + 1; else hi = mid; }
  const int end = lo;
  const int cntg = end - start;
  const float inv = cntg > 0 ? 1.0f / (float)cntg : 0.0f;

  for (int d = tid; d < D_DIM; d += 256) {
    float s = 0.0f;
    for (int i = start; i < end; ++i) s += x[(size_t)i * D_DIM + d];
    xg[d] = s * inv;
  }
  const int b = dataset_name[g];
  __syncthreads();

  const float* __restrict__ W1 = Wg_shared + (size_t)b * D_DIM * H_DIM;
  for (int h = tid; h < H_DIM; h += 256) {
    float s = bg_shared[b * H_DIM + h];
    for (int d = 0; d < D_DIM; ++d) s += xg[d] * W1[(size_t)d * H_DIM + h];
    hg[h] = fmaxf(s, 0.0f);
  }
  __syncthreads();

  const float* __restrict__ W2 = Wg_head + (size_t)b * H_DIM * 2 * GHD;
  if (tid < 2 * GHD) {
    float s = bg_head[b * 2 * GHD + tid];
    for (int h = 0; h < H_DIM; ++h) s += hg[h] * W2[(size_t)h * 2 * GHD + tid];
    if (tid < GHD) out[g * GHD + tid] = s;
    else           out[GV_OFF + g * GHD + (tid - GHD)] = s * s;
  }
}

// ---------------------------------------------------------------------------
// Kernel C: node path grouped GEMM. BM=32 rows (gathered per-branch), full
// 512-wide output per block, BK=16 K-tiles. Fused 512->6 second layer in the
// epilogue (no hn materialization).
// thread layout: tx = tid&31 (col group), ty = tid>>5 (row group 0..7)
// thread owns rows ty*4..ty*4+3, cols {2*tx + 64*j, 2*tx+1 + 64*j} j=0..7
// ---------------------------------------------------------------------------
#define BM 32
#define BK 16

__global__ __launch_bounds__(256) void node_kernel(
    const float* __restrict__ x,
    const float* __restrict__ Wn1, const float* __restrict__ bn1,
    const float* __restrict__ Wn2, const float* __restrict__ bn2,
    const int* __restrict__ cnt, const int* __restrict__ lists,
    float* __restrict__ out) {
  __shared__ float As[BK][BM];       // 2 KB, transposed: As[k][r]
  __shared__ float Bs[BK][D_DIM];    // 32 KB
  __shared__ float W2s[D_DIM][6];    // 12 KB
  __shared__ float on_lds[BM][8];    // 1 KB (pad 6->8)
  __shared__ int nidx[BM];

  const int tile = blockIdx.x & 1023;
  const int b = blockIdx.x >> 10;
  const int count = cnt[b];
  const int base = tile * BM;
  if (base >= count) return;

  const int tid = threadIdx.x;
  const int tx = tid & 31;
  const int ty = tid >> 5;

  if (tid < BM) {
    int r = base + tid;
    nidx[tid] = (r < count) ? lists[b * N_NODES + r] : -1;
  }
  // stage Wn2[b] (512x6)
  for (int i = tid; i < D_DIM * 6; i += 256) {
    W2s[i / 6][i % 6] = Wn2[(size_t)b * D_DIM * 6 + i];
  }
  // zero epilogue accumulators
  on_lds[tid >> 3][tid & 7] = 0.0f;

  // init acc with bn1 bias (same bias for all 4 rows)
  float acc[4][16];
  const float* __restrict__ bn1b = bn1 + (size_t)b * D_DIM;
#pragma unroll
  for (int j = 0; j < 8; ++j) {
    float b0 = bn1b[2 * tx + 64 * j];
    float b1 = bn1b[2 * tx + 1 + 64 * j];
#pragma unroll
    for (int i = 0; i < 4; ++i) { acc[i][2 * j] = b0; acc[i][2 * j + 1] = b1; }
  }

  const float* __restrict__ W1 = Wn1 + (size_t)b * D_DIM * D_DIM;

  for (int k0 = 0; k0 < D_DIM; k0 += BK) {
    __syncthreads();  // also covers nidx/W2s/on_lds init on first iter
    // load A tile: 32 rows x 16 k, float4 along k by threads 0..127
    if (tid < 128) {
      int r = tid >> 2, kq = tid & 3;
      int n = nidx[r];
      float4 v = make_float4(0.f, 0.f, 0.f, 0.f);
      if (n >= 0) v = *reinterpret_cast<const float4*>(&x[(size_t)n * D_DIM + k0 + kq * 4]);
      As[kq * 4 + 0][r] = v.x;
      As[kq * 4 + 1][r] = v.y;
      As[kq * 4 + 2][r] = v.z;
      As[kq * 4 + 3][r] = v.w;
    }
    // load B tile: 16 x 512 floats as float4, coalesced
#pragma unroll
    for (int e = tid; e < BK * D_DIM / 4; e += 256) {
      int k = e >> 7, c4 = e & 127;
      float4 v = *reinterpret_cast<const float4*>(&W1[(size_t)(k0 + k) * D_DIM + c4 * 4]);
      *reinterpret_cast<float4*>(&Bs[k][c4 * 4]) = v;
    }
    __syncthreads();
#pragma unroll
    for (int k = 0; k < BK; ++k) {
      float4 av = *reinterpret_cast<const float4*>(&As[k][ty * 4]);
#pragma unroll
      for (int j = 0; j < 8; ++j) {
        float2 bv = *reinterpret_cast<const float2*>(&Bs[k][2 * tx + 64 * j]);
        acc[0][2 * j]     += av.x * bv.x;  acc[0][2 * j + 1] += av.x * bv.y;
        acc[1][2 * j]     += av.y * bv.x;  acc[1][2 * j + 1] += av.y * bv.y;
        acc[2][2 * j]     += av.z * bv.x;  acc[2][2 * j + 1] += av.z * bv.y;
        acc[3][2 * j]     += av.w * bv.x;  acc[3][2 * j + 1] += av.w * bv.y;
      }
    }
  }

  // relu
#pragma unroll
  for (int i = 0; i < 4; ++i)
#pragma unroll
    for (int j = 0; j < 16; ++j) acc[i][j] = fmaxf(acc[i][j], 0.0f);

  __syncthreads();  // ensure on_lds zeros + last Bs use done

  // fused second layer: partial on[r][o] over this thread's 16 cols
#pragma unroll
  for (int i = 0; i < 4; ++i) {
    float p0 = 0.f, p1 = 0.f, p2 = 0.f, p3 = 0.f, p4 = 0.f, p5 = 0.f;
#pragma unroll
    for (int j = 0; j < 8; ++j) {
      int c0 = 2 * tx + 64 * j;
#pragma unroll
      for (int u = 0; u < 2; ++u) {
        float a = acc[i][2 * j + u];
        int c = c0 + u;
        p0 += a * W2s[c][0]; p1 += a * W2s[c][1]; p2 += a * W2s[c][2];
        p3 += a * W2s[c][3]; p4 += a * W2s[c][4]; p5 += a * W2s[c][5];
      }
    }
    int r = ty * 4 + i;
    atomicAdd(&on_lds[r][0], p0); atomicAdd(&on_lds[r][1], p1);
    atomicAdd(&on_lds[r][2], p2); atomicAdd(&on_lds[r][3], p3);
    atomicAdd(&on_lds[r][4], p4); atomicAdd(&on_lds[r][5], p5);
  }
  __syncthreads();

  if (tid < BM * 6) {
    int r = tid / 6, o = tid % 6;
    if (base + r < count) {
      int n = nidx[r];
      float v = on_lds[r][o] + bn2[b * 6 + o];
      if (o < NHD) out[NH_OFF + n * NHD + o] = v;
      else         out[NV_OFF + n * NHD + (o - NHD)] = v * v;
    }
  }
}

// ---------------------------------------------------------------------------
extern "C" void kernel_launch(void* const* d_in, const int* in_sizes, int n_in,
                              void* d_out, int out_size, void* d_ws, size_t ws_size,
                              hipStream_t stream) {
  const float* x         = (const float*)d_in[0];
  const int*   batch     = (const int*)d_in[1];
  const int*   dsname    = (const int*)d_in[2];
  const float* Wg_shared = (const float*)d_in[3];
  const float* bg_shared = (const float*)d_in[4];
  const float* Wg_head   = (const float*)d_in[5];
  const float* bg_head   = (const float*)d_in[6];
  const float* Wn1       = (const float*)d_in[7];
  const float* bn1       = (const float*)d_in[8];
  const float* Wn2       = (const float*)d_in[9];
  const float* bn2       = (const float*)d_in[10];
  float* out = (float*)d_out;

  int* cnt   = (int*)d_ws;                 // 4 counters (64B slot)
  int* lists = (int*)d_ws + 16;            // 4 * N_NODES ints

  hipMemsetAsync(cnt, 0, 4 * sizeof(int), stream);
  build_lists_kernel<<<N_NODES / 256, 256, 0, stream>>>(batch, dsname, cnt, lists);
  graph_kernel<<<G_GRAPHS, 256, 0, stream>>>(x, batch, dsname, Wg_shared, bg_shared,
                                             Wg_head, bg_head, out);
  node_kernel<<<B_BR * (N_NODES / BM), 256, 0, stream>>>(x, Wn1, bn1, Wn2, bn2,
                                                         cnt, lists, out);
}

// Round 2
// 750.144 us; speedup vs baseline: 1.1653x; 1.1653x over previous
//
#include <hip/hip_runtime.h>

#define N_NODES 32768
#define G_GRAPHS 1024
#define D_DIM 512
#define H_DIM 768
#define B_BR 4
#define GHD 64
#define NHD 3

// output layout (f32, concatenated flat)
#define NH_OFF (G_GRAPHS * GHD)
#define GV_OFF (G_GRAPHS * GHD + N_NODES * NHD)
#define NV_OFF (2 * G_GRAPHS * GHD + N_NODES * NHD)

typedef unsigned short ushort_t;
typedef __attribute__((ext_vector_type(8))) short short8;
typedef __attribute__((ext_vector_type(4))) float f32x4;

// ---------------------------------------------------------------------------
// build per-branch node index lists
// ---------------------------------------------------------------------------
__global__ __launch_bounds__(256) void build_lists_kernel(
    const int* __restrict__ batch, const int* __restrict__ dataset_name,
    int* __restrict__ cnt, int* __restrict__ lists) {
  int n = blockIdx.x * 256 + threadIdx.x;
  if (n >= N_NODES) return;
  int b = dataset_name[batch[n]];
  int pos = atomicAdd(&cnt[b], 1);
  lists[b * N_NODES + pos] = n;
}

__global__ __launch_bounds__(256) void build_glist_kernel(
    const int* __restrict__ dsname, int* __restrict__ gcnt, int* __restrict__ glist) {
  int g = blockIdx.x * 256 + threadIdx.x;
  if (g >= G_GRAPHS) return;
  int b = dsname[g];
  int pos = atomicAdd(&gcnt[b], 1);
  glist[b * G_GRAPHS + pos] = g;
}

// ---------------------------------------------------------------------------
// Wn1 [b][k][n] f32 -> WT_hi/WT_lo [b][n][k] bf16 (hi = trunc, lo = residual)
// ---------------------------------------------------------------------------
__global__ __launch_bounds__(256) void conv_w_kernel(
    const float* __restrict__ Wn1, ushort_t* __restrict__ WT_hi,
    ushort_t* __restrict__ WT_lo) {
  __shared__ float Ws[64][65];
  int b = blockIdx.x >> 6;
  int t = blockIdx.x & 63;
  int kt = t >> 3, nt = t & 7;
  const float* W = Wn1 + (size_t)b * D_DIM * D_DIM;
  for (int i = threadIdx.x; i < 64 * 64; i += 256) {
    int k = i >> 6, n = i & 63;
    Ws[k][n] = W[(size_t)(kt * 64 + k) * D_DIM + nt * 64 + n];
  }
  __syncthreads();
  for (int i = threadIdx.x; i < 64 * 64; i += 256) {
    int n = i >> 6, k = i & 63;
    float v = Ws[k][n];
    unsigned bits = __float_as_uint(v);
    ushort_t hi = (ushort_t)(bits >> 16);
    float hf = __uint_as_float(bits & 0xffff0000u);
    float r = v - hf;
    ushort_t lo = (ushort_t)(__float_as_uint(r) >> 16);
    size_t o = ((size_t)b * D_DIM + nt * 64 + n) * D_DIM + kt * 64 + k;
    WT_hi[o] = hi;
    WT_lo[o] = lo;
  }
}

// Wn2 [b][c][o] (o<6) -> W2T [b][o][c], o padded to 16 with zeros, bf16 RNE
__global__ __launch_bounds__(256) void conv_w2_kernel(
    const float* __restrict__ Wn2, ushort_t* __restrict__ W2T) {
  int b = blockIdx.x;
  for (int i = threadIdx.x; i < 16 * D_DIM; i += 256) {
    int o = i & 15, c = i >> 4;
    float v = (o < 6) ? Wn2[(size_t)b * D_DIM * 6 + c * 6 + o] : 0.0f;
    unsigned bits = __float_as_uint(v);
    ushort_t hv = (ushort_t)((bits + 0x7fffu + ((bits >> 16) & 1u)) >> 16);
    W2T[(size_t)b * 16 * D_DIM + o * D_DIM + c] = hv;
  }
}

// ---------------------------------------------------------------------------
// mean-pool per graph -> xg[1024][512] f32
// ---------------------------------------------------------------------------
__global__ __launch_bounds__(128) void pool_kernel(
    const float* __restrict__ x, const int* __restrict__ batch,
    float* __restrict__ xg) {
  const int g = blockIdx.x;
  const int tid = threadIdx.x;
  int lo = 0, hi = N_NODES;
  while (lo < hi) { int mid = (lo + hi) >> 1; if (batch[mid] < g) lo = mid + 1; else hi = mid; }
  const int start = lo;
  hi = N_NODES;
  while (lo < hi) { int mid = (lo + hi) >> 1; if (batch[mid] < g + 1) lo = mid + 1; else hi = mid; }
  const int end = lo;
  const float inv = (end > start) ? 1.0f / (float)(end - start) : 0.0f;
  float4 acc = make_float4(0.f, 0.f, 0.f, 0.f);
  for (int i = start; i < end; ++i) {
    float4 v = *reinterpret_cast<const float4*>(&x[(size_t)i * D_DIM + tid * 4]);
    acc.x += v.x; acc.y += v.y; acc.z += v.z; acc.w += v.w;
  }
  acc.x *= inv; acc.y *= inv; acc.z *= inv; acc.w *= inv;
  *reinterpret_cast<float4*>(&xg[(size_t)g * D_DIM + tid * 4]) = acc;
}

// ---------------------------------------------------------------------------
// node path: MFMA grouped GEMM, 32 gathered rows x 512 cols per block.
// hi/lo split bf16: acc += Al*Bh + Ah*Bl + Ah*Bh  (~f32 accuracy)
// second layer fused via one extra MFMA per 16-row tile against W2T.
// ---------------------------------------------------------------------------
__global__ __launch_bounds__(256) void node_mfma_kernel(
    const float* __restrict__ x,
    const ushort_t* __restrict__ WT_hi, const ushort_t* __restrict__ WT_lo,
    const float* __restrict__ bn1,
    const ushort_t* __restrict__ W2T, const float* __restrict__ bn2,
    const int* __restrict__ cnt, const int* __restrict__ lists,
    float* __restrict__ out) {
  __shared__ float As[32 * 512];   // 64 KB, 16B-granule XOR swizzled
  __shared__ int nidx[32];

  const int tile = blockIdx.x & 1023;
  const int b = blockIdx.x >> 10;
  const int count = cnt[b];
  const int base = tile * 32;
  if (base >= count) return;

  const int tid = threadIdx.x;
  const int lane = tid & 63;
  const int w = tid >> 6;
  const int l15 = lane & 15;
  const int lq = lane >> 4;

  if (tid < 32) {
    int r = base + tid;
    nidx[tid] = (r < count) ? lists[b * N_NODES + r] : lists[b * N_NODES];
  }
  __syncthreads();

  // stage A: 32 rows x 512 f32. unit = 16B chunk; swizzle word idx ^ (r&7)*4
#pragma unroll
  for (int it = 0; it < 16; ++it) {
    int u = tid + 256 * it;
    int r = u >> 7, c16 = u & 127;
    float4 v = *reinterpret_cast<const float4*>(&x[(size_t)nidx[r] * D_DIM + c16 * 4]);
    int dw = r * 512 + ((c16 * 4) ^ ((r & 7) * 4));
    *reinterpret_cast<float4*>(&As[dw]) = v;
  }
  __syncthreads();

  f32x4 acc[2][8];
#pragma unroll
  for (int i = 0; i < 2; ++i)
#pragma unroll
    for (int j = 0; j < 8; ++j) acc[i][j] = (f32x4){0.f, 0.f, 0.f, 0.f};

  const size_t wbase = (size_t)b * (512 * 512) + (size_t)(w * 128 + l15) * 512 + lq * 8;
  const ushort_t* __restrict__ wh = WT_hi + wbase;
  const ushort_t* __restrict__ wl = WT_lo + wbase;

#pragma unroll 2
  for (int ks = 0; ks < 16; ++ks) {
    const int k0 = ks * 32;
    const int kb = k0 + lq * 8;
    short8 ah[2], al[2];
#pragma unroll
    for (int rt = 0; rt < 2; ++rt) {
      int R = rt * 16 + l15;
      int sw = (R & 7) * 4;
      int bw = R * 512;
      float4 f0 = *reinterpret_cast<const float4*>(&As[bw + (kb ^ sw)]);
      float4 f1 = *reinterpret_cast<const float4*>(&As[bw + ((kb + 4) ^ sw)]);
      float fv[8] = {f0.x, f0.y, f0.z, f0.w, f1.x, f1.y, f1.z, f1.w};
      short8 sh, sl;
#pragma unroll
      for (int j = 0; j < 8; ++j) {
        unsigned bits = __float_as_uint(fv[j]);
        sh[j] = (short)(bits >> 16);
        float rr = fv[j] - __uint_as_float(bits & 0xffff0000u);
        sl[j] = (short)(__float_as_uint(rr) >> 16);
      }
      ah[rt] = sh;
      al[rt] = sl;
    }
#pragma unroll
    for (int ct = 0; ct < 8; ++ct) {
      short8 bh = *reinterpret_cast<const short8*>(wh + ct * 8192 + k0);
      short8 bl = *reinterpret_cast<const short8*>(wl + ct * 8192 + k0);
#pragma unroll
      for (int rt = 0; rt < 2; ++rt) {
        acc[rt][ct] = __builtin_amdgcn_mfma_f32_16x16x32_bf16(al[rt], bh, acc[rt][ct], 0, 0, 0);
        acc[rt][ct] = __builtin_amdgcn_mfma_f32_16x16x32_bf16(ah[rt], bl, acc[rt][ct], 0, 0, 0);
        acc[rt][ct] = __builtin_amdgcn_mfma_f32_16x16x32_bf16(ah[rt], bh, acc[rt][ct], 0, 0, 0);
      }
    }
  }

  __syncthreads();  // done reading As; reuse as bf16 hn tile
  ushort_t* hn = (ushort_t*)As;
#pragma unroll
  for (int ct = 0; ct < 8; ++ct) {
    int n = w * 128 + ct * 16 + l15;
    float bias = bn1[b * D_DIM + n];
#pragma unroll
    for (int rt = 0; rt < 2; ++rt) {
#pragma unroll
      for (int j = 0; j < 4; ++j) {
        int row = rt * 16 + lq * 4 + j;
        float v = fmaxf(acc[rt][ct][j] + bias, 0.0f);
        unsigned bits = __float_as_uint(v);
        ushort_t hv = (ushort_t)((bits + 0x7fffu + ((bits >> 16) & 1u)) >> 16);
        int byteoff = row * 1024 + ((n * 2) ^ ((row & 7) * 16));
        hn[byteoff >> 1] = hv;
      }
    }
  }
  __syncthreads();

  // second layer: waves 0,1 each handle one 16-row tile. D2[m][o<16]
  if (w < 2) {
    const int rt = w;
    f32x4 acc2 = (f32x4){0.f, 0.f, 0.f, 0.f};
    const ushort_t* __restrict__ w2 = W2T + (size_t)b * (16 * 512) + (size_t)l15 * 512 + lq * 8;
    const int R = rt * 16 + l15;
#pragma unroll
    for (int ks = 0; ks < 16; ++ks) {
      int kb = ks * 32 + lq * 8;
      int byteoff = R * 1024 + ((kb * 2) ^ ((R & 7) * 16));
      short8 a2 = *reinterpret_cast<const short8*>((const char*)hn + byteoff);
      short8 b2 = *reinterpret_cast<const short8*>(w2 + ks * 32);
      acc2 = __builtin_amdgcn_mfma_f32_16x16x32_bf16(a2, b2, acc2, 0, 0, 0);
    }
    int o = l15;
    if (o < 6) {
      float bo = bn2[b * 6 + o];
#pragma unroll
      for (int j = 0; j < 4; ++j) {
        int r = rt * 16 + lq * 4 + j;
        if (base + r < count) {
          int n = nidx[r];
          float v = acc2[j] + bo;
          if (o < NHD) out[NH_OFF + n * NHD + o] = v;
          else out[NV_OFF + n * NHD + (o - NHD)] = v * v;
        }
      }
    }
  }
}

// ---------------------------------------------------------------------------
// graph layer1: branch-grouped f32 tiles, 16 graphs x 96 cols per block
// ---------------------------------------------------------------------------
__global__ __launch_bounds__(256) void graph_l1_kernel(
    const float* __restrict__ xg, const float* __restrict__ Wg_shared,
    const float* __restrict__ bg_shared,
    const int* __restrict__ gcnt, const int* __restrict__ glist,
    float* __restrict__ hg) {
  __shared__ float As[16][16];
  __shared__ float Bs[16][96];
  __shared__ int gidx[16];
  const int bid = blockIdx.x;          // b(4) x tile(64) x cb(8)
  const int b = bid >> 9;
  const int t = bid & 511;
  const int tile = t >> 3, cb = t & 7;
  const int gc = gcnt[b];
  const int base = tile * 16;
  if (base >= gc) return;
  const int tid = threadIdx.x;
  const int tx = tid & 31, ty = tid >> 5;
  if (tid < 16) gidx[tid] = (base + tid < gc) ? glist[b * G_GRAPHS + base + tid] : glist[b * G_GRAPHS];
  float acc[2][3] = {{0.f, 0.f, 0.f}, {0.f, 0.f, 0.f}};
  const float* __restrict__ W1 = Wg_shared + (size_t)b * D_DIM * H_DIM + cb * 96;
  for (int k0 = 0; k0 < D_DIM; k0 += 16) {
    __syncthreads();
    if (tid < 64) {
      int r = tid >> 2, kq = tid & 3;
      float4 v = *reinterpret_cast<const float4*>(&xg[(size_t)gidx[r] * D_DIM + k0 + kq * 4]);
      As[kq * 4 + 0][r] = v.x; As[kq * 4 + 1][r] = v.y;
      As[kq * 4 + 2][r] = v.z; As[kq * 4 + 3][r] = v.w;
    }
    for (int e = tid; e < 16 * 24; e += 256) {
      int k = e / 24, c4 = e % 24;
      *reinterpret_cast<float4*>(&Bs[k][c4 * 4]) =
          *reinterpret_cast<const float4*>(&W1[(size_t)(k0 + k) * H_DIM + c4 * 4]);
    }
    __syncthreads();
#pragma unroll
    for (int k = 0; k < 16; ++k) {
      float a0 = As[k][ty * 2], a1 = As[k][ty * 2 + 1];
#pragma unroll
      for (int j = 0; j < 3; ++j) {
        float bv = Bs[k][tx + 32 * j];
        acc[0][j] += a0 * bv;
        acc[1][j] += a1 * bv;
      }
    }
  }
#pragma unroll
  for (int i = 0; i < 2; ++i) {
    int rr = ty * 2 + i;
    if (base + rr < gc) {
      int g = gidx[rr];
#pragma unroll
      for (int j = 0; j < 3; ++j) {
        int h = cb * 96 + tx + 32 * j;
        float v = fmaxf(acc[i][j] + bg_shared[b * H_DIM + h], 0.f);
        hg[(size_t)g * H_DIM + h] = v;
      }
    }
  }
}

// ---------------------------------------------------------------------------
// graph layer2: 8 graphs per block, hg staged in LDS, coalesced W reads
// ---------------------------------------------------------------------------
__global__ __launch_bounds__(256) void graph_l2_kernel(
    const float* __restrict__ hg, const float* __restrict__ Wg_head,
    const float* __restrict__ bg_head,
    const int* __restrict__ gcnt, const int* __restrict__ glist,
    float* __restrict__ out) {
  __shared__ float hs[8][H_DIM];
  __shared__ int gidx[8];
  const int b = blockIdx.x >> 7;
  const int tile = blockIdx.x & 127;
  const int gc = gcnt[b];
  if (tile * 8 >= gc) return;
  const int tid = threadIdx.x;
  if (tid < 8) gidx[tid] = (tile * 8 + tid < gc) ? glist[b * G_GRAPHS + tile * 8 + tid] : -1;
  __syncthreads();
  for (int e = tid; e < 8 * 192; e += 256) {
    int r = e / 192, c4 = e % 192;
    int g = gidx[r];
    float4 v = make_float4(0.f, 0.f, 0.f, 0.f);
    if (g >= 0) v = *reinterpret_cast<const float4*>(&hg[(size_t)g * H_DIM + c4 * 4]);
    *reinterpret_cast<float4*>(&hs[r][c4 * 4]) = v;
  }
  __syncthreads();
  const float* __restrict__ W2 = Wg_head + (size_t)b * H_DIM * 2 * GHD;
  const float* __restrict__ bh = bg_head + b * 2 * GHD;
#pragma unroll
  for (int it = 0; it < 4; ++it) {
    int idx = it * 256 + tid;
    int r = idx >> 7, o = idx & 127;
    int g = gidx[r];
    if (g < 0) continue;
    float s = bh[o];
#pragma unroll 4
    for (int h = 0; h < H_DIM; ++h) s += hs[r][h] * W2[(size_t)h * 2 * GHD + o];
    if (o < GHD) out[g * GHD + o] = s;
    else out[GV_OFF + g * GHD + (o - GHD)] = s * s;
  }
}

// ---------------------------------------------------------------------------
extern "C" void kernel_launch(void* const* d_in, const int* in_sizes, int n_in,
                              void* d_out, int out_size, void* d_ws, size_t ws_size,
                              hipStream_t stream) {
  const float* x         = (const float*)d_in[0];
  const int*   batch     = (const int*)d_in[1];
  const int*   dsname    = (const int*)d_in[2];
  const float* Wg_shared = (const float*)d_in[3];
  const float* bg_shared = (const float*)d_in[4];
  const float* Wg_head   = (const float*)d_in[5];
  const float* bg_head   = (const float*)d_in[6];
  const float* Wn1       = (const float*)d_in[7];
  const float* bn1       = (const float*)d_in[8];
  const float* Wn2       = (const float*)d_in[9];
  const float* bn2       = (const float*)d_in[10];
  float* out = (float*)d_out;

  int* ws_i  = (int*)d_ws;
  int* cnt   = ws_i;              // [0,4)
  int* gcnt  = ws_i + 16;         // [16,20)
  int* lists = ws_i + 32;         // 4*32768
  int* glist = ws_i + 131104;     // 4*1024
  float* xg  = (float*)(ws_i + 135232);      // 1024*512 f32
  float* hg  = xg + 524288;                  // 1024*768 f32
  ushort_t* WT_hi = (ushort_t*)(hg + 786432);  // 4*512*512 bf16
  ushort_t* WT_lo = WT_hi + 1048576;
  ushort_t* W2T   = WT_lo + 1048576;           // 4*16*512 bf16

  hipMemsetAsync(d_ws, 0, 128, stream);
  build_lists_kernel<<<N_NODES / 256, 256, 0, stream>>>(batch, dsname, cnt, lists);
  build_glist_kernel<<<G_GRAPHS / 256, 256, 0, stream>>>(dsname, gcnt, glist);
  conv_w_kernel<<<256, 256, 0, stream>>>(Wn1, WT_hi, WT_lo);
  conv_w2_kernel<<<4, 256, 0, stream>>>(Wn2, W2T);
  pool_kernel<<<G_GRAPHS, 128, 0, stream>>>(x, batch, xg);
  node_mfma_kernel<<<B_BR * (N_NODES / 32), 256, 0, stream>>>(
      x, WT_hi, WT_lo, bn1, W2T, bn2, cnt, lists, out);
  graph_l1_kernel<<<2048, 256, 0, stream>>>(xg, Wg_shared, bg_shared, gcnt, glist, hg);
  graph_l2_kernel<<<512, 256, 0, stream>>>(hg, Wg_head, bg_head, gcnt, glist, out);
}

// Round 4
// 353.592 us; speedup vs baseline: 2.4722x; 2.1215x over previous
//
#include <hip/hip_runtime.h>

#define N_NODES 32768
#define G_GRAPHS 1024
#define D_DIM 512
#define H_DIM 768
#define B_BR 4
#define GHD 64
#define NHD 3

// output layout (f32, concatenated flat)
#define NH_OFF (G_GRAPHS * GHD)
#define GV_OFF (G_GRAPHS * GHD + N_NODES * NHD)
#define NV_OFF (2 * G_GRAPHS * GHD + N_NODES * NHD)

typedef unsigned short ushort_t;
typedef __attribute__((ext_vector_type(8))) short short8;
typedef __attribute__((ext_vector_type(4))) float f32x4;
typedef __attribute__((ext_vector_type(4))) ushort_t ushort4_t;

// ---------------------------------------------------------------------------
// per-graph segment bounds (batch is sorted)
// ---------------------------------------------------------------------------
__global__ __launch_bounds__(256) void seg_kernel(
    const int* __restrict__ batch, int* __restrict__ gstart) {
  int g = blockIdx.x * 256 + threadIdx.x;
  if (g > G_GRAPHS) return;
  if (g == G_GRAPHS) { gstart[G_GRAPHS] = N_NODES; return; }
  int lo = 0, hi = N_NODES;
  while (lo < hi) { int mid = (lo + hi) >> 1; if (batch[mid] < g) lo = mid + 1; else hi = mid; }
  gstart[g] = lo;
}

// ---------------------------------------------------------------------------
// 4-wave scan: wave b handles branch b. Produces per-graph node offsets
// (within branch), branch node counts, branch graph lists + counts. No atomics.
// ---------------------------------------------------------------------------
__global__ __launch_bounds__(256) void scan_kernel(
    const int* __restrict__ dsname, const int* __restrict__ gstart,
    int* __restrict__ goff, int* __restrict__ glist,
    int* __restrict__ cnt, int* __restrict__ gcnt) {
  const int lane = threadIdx.x & 63;
  const int b = threadIdx.x >> 6;
  int run_n = 0, run_g = 0;
  for (int c = 0; c < G_GRAPHS / 64; ++c) {
    int g = c * 64 + lane;
    int mine = (dsname[g] == b) ? 1 : 0;
    int len = mine ? (gstart[g + 1] - gstart[g]) : 0;
    int sl = len, so = mine;
#pragma unroll
    for (int off = 1; off < 64; off <<= 1) {
      int tl = __shfl_up(sl, off);
      int to = __shfl_up(so, off);
      if (lane >= off) { sl += tl; so += to; }
    }
    if (mine) {
      goff[g] = run_n + sl - len;
      glist[b * G_GRAPHS + run_g + so - 1] = g;
    }
    run_n += __shfl(sl, 63);
    run_g += __shfl(so, 63);
  }
  if (lane == 0) { cnt[b] = run_n; gcnt[b] = run_g; }
}

// ---------------------------------------------------------------------------
// scatter nodes into per-branch lists (atomic-free, ordered by node id)
// ---------------------------------------------------------------------------
__global__ __launch_bounds__(256) void scatter_kernel(
    const int* __restrict__ batch, const int* __restrict__ dsname,
    const int* __restrict__ gstart, const int* __restrict__ goff,
    int* __restrict__ lists) {
  int n = blockIdx.x * 256 + threadIdx.x;
  int g = batch[n];
  int b = dsname[g];
  lists[b * N_NODES + goff[g] + (n - gstart[g])] = n;
}

// ---------------------------------------------------------------------------
// Wn1 [b][k][n] f32 -> packed MFMA-fragment-order bf16 hi/lo:
// WP[b][n16][ks][lane][8] where lane = lq*16 + l15 holds
// (col n16*16+l15, k = ks*32 + lq*8 + j)
// ---------------------------------------------------------------------------
__global__ __launch_bounds__(256) void conv_w_kernel(
    const float* __restrict__ Wn1, ushort_t* __restrict__ WPh,
    ushort_t* __restrict__ WPl) {
  __shared__ float Ws[64][65];
  int b = blockIdx.x >> 6;
  int t = blockIdx.x & 63;
  int kt = t >> 3, nt = t & 7;
  const float* W = Wn1 + (size_t)b * D_DIM * D_DIM;
  for (int i = threadIdx.x; i < 64 * 64; i += 256) {
    int k = i >> 6, n = i & 63;
    Ws[k][n] = W[(size_t)(kt * 64 + k) * D_DIM + nt * 64 + n];
  }
  __syncthreads();
  for (int i = threadIdx.x; i < 64 * 8; i += 256) {
    int n = i >> 3, kq8 = i & 7;
    short8 sh, sl;
#pragma unroll
    for (int j = 0; j < 8; ++j) {
      float v = Ws[kq8 * 8 + j][n];
      unsigned bits = __float_as_uint(v);
      sh[j] = (short)(bits >> 16);
      float r = v - __uint_as_float(bits & 0xffff0000u);
      sl[j] = (short)(__float_as_uint(r) >> 16);
    }
    int gn = nt * 64 + n, gk0 = kt * 64 + kq8 * 8;
    int n16 = gn >> 4, l15 = gn & 15;
    int ks = gk0 >> 5, lq = (gk0 >> 3) & 3;
    size_t off = ((((size_t)b * 32 + n16) * 16 + ks) * 64 + lq * 16 + l15) * 8;
    *reinterpret_cast<short8*>(WPh + off) = sh;
    *reinterpret_cast<short8*>(WPl + off) = sl;
  }
}

// Wn2 [b][c][o] (o<6) -> W2T [b][o][c], o padded to 16 with zeros, bf16 RNE
__global__ __launch_bounds__(256) void conv_w2_kernel(
    const float* __restrict__ Wn2, ushort_t* __restrict__ W2T) {
  int b = blockIdx.x;
  for (int i = threadIdx.x; i < 16 * D_DIM; i += 256) {
    int o = i & 15, c = i >> 4;
    float v = (o < 6) ? Wn2[(size_t)b * D_DIM * 6 + c * 6 + o] : 0.0f;
    unsigned bits = __float_as_uint(v);
    ushort_t hv = (ushort_t)((bits + 0x7fffu + ((bits >> 16) & 1u)) >> 16);
    W2T[(size_t)b * 16 * D_DIM + o * D_DIM + c] = hv;
  }
}

// ---------------------------------------------------------------------------
// mean-pool per graph -> xg[1024][512] f32
// ---------------------------------------------------------------------------
__global__ __launch_bounds__(128) void pool_kernel(
    const float* __restrict__ x, const int* __restrict__ gstart,
    float* __restrict__ xg) {
  const int g = blockIdx.x;
  const int tid = threadIdx.x;
  const int start = gstart[g], end = gstart[g + 1];
  const float inv = (end > start) ? 1.0f / (float)(end - start) : 0.0f;
  float4 acc = make_float4(0.f, 0.f, 0.f, 0.f);
  for (int i = start; i < end; ++i) {
    float4 v = *reinterpret_cast<const float4*>(&x[(size_t)i * D_DIM + tid * 4]);
    acc.x += v.x; acc.y += v.y; acc.z += v.z; acc.w += v.w;
  }
  acc.x *= inv; acc.y *= inv; acc.z *= inv; acc.w *= inv;
  *reinterpret_cast<float4*>(&xg[(size_t)g * D_DIM + tid * 4]) = acc;
}

// ---------------------------------------------------------------------------
// node path: MFMA grouped GEMM, 32 gathered rows x 512 cols per block.
// A staged as bf16 hi/lo in LDS (converted once, XOR-swizzled for ds_read_b128)
// B streamed from packed fragment-order buffers (coalesced dwordx4).
// acc += Al*Bh + Ah*Bl + Ah*Bh (~f32 accuracy). Layer2 fused via one MFMA.
// ---------------------------------------------------------------------------
__global__ __launch_bounds__(256) void node_mfma_kernel(
    const float* __restrict__ x,
    const ushort_t* __restrict__ WPh, const ushort_t* __restrict__ WPl,
    const float* __restrict__ bn1,
    const ushort_t* __restrict__ W2T, const float* __restrict__ bn2,
    const int* __restrict__ cnt, const int* __restrict__ lists,
    float* __restrict__ out) {
  __shared__ ushort_t Ah[32 * 512];  // 32 KB
  __shared__ ushort_t Al[32 * 512];  // 32 KB
  __shared__ int nidx[32];

  const int tile = blockIdx.x & 1023;
  const int b = blockIdx.x >> 10;
  const int count = cnt[b];
  const int base = tile * 32;
  if (base >= count) return;

  const int tid = threadIdx.x;
  const int lane = tid & 63;
  const int w = tid >> 6;
  const int l15 = lane & 15;
  const int lq = lane >> 4;

  if (tid < 32) {
    int r = base + tid;
    nidx[tid] = (r < count) ? lists[b * N_NODES + r] : lists[b * N_NODES];
  }
  __syncthreads();

  // stage A: convert f32 -> bf16 hi/lo during staging; swizzle byte^((r&7)<<4)
  // 32 rows x 128 float4-chunks = 4096 units over 16 iterations of 256 threads
#pragma unroll
  for (int it = 0; it < 16; ++it) {
    int u = it * 256 + tid;
    int r = u >> 7, c4 = u & 127;
    float4 v = *reinterpret_cast<const float4*>(&x[(size_t)nidx[r] * D_DIM + c4 * 4]);
    float fv[4] = {v.x, v.y, v.z, v.w};
    ushort4_t h4, l4;
#pragma unroll
    for (int j = 0; j < 4; ++j) {
      unsigned bits = __float_as_uint(fv[j]);
      h4[j] = (ushort_t)(bits >> 16);
      float rr = fv[j] - __uint_as_float(bits & 0xffff0000u);
      l4[j] = (ushort_t)(__float_as_uint(rr) >> 16);
    }
    int byteoff = r * 1024 + ((c4 * 8) ^ ((r & 7) << 4));
    *reinterpret_cast<ushort4_t*>((char*)Ah + byteoff) = h4;
    *reinterpret_cast<ushort4_t*>((char*)Al + byteoff) = l4;
  }
  __syncthreads();

  f32x4 acc[2][8];
#pragma unroll
  for (int i = 0; i < 2; ++i)
#pragma unroll
    for (int j = 0; j < 8; ++j) acc[i][j] = (f32x4){0.f, 0.f, 0.f, 0.f};

  const size_t wpo = (((size_t)b * 32 + w * 8) * 16) * 512 + (size_t)lane * 8;
  const ushort_t* __restrict__ wph = WPh + wpo;
  const ushort_t* __restrict__ wpl = WPl + wpo;

  for (int ks = 0; ks < 16; ++ks) {
    short8 ah[2], al[2];
#pragma unroll
    for (int rt = 0; rt < 2; ++rt) {
      int R = rt * 16 + l15;
      int byteoff = R * 1024 + ((ks * 64 + lq * 16) ^ ((R & 7) << 4));
      ah[rt] = *reinterpret_cast<const short8*>((const char*)Ah + byteoff);
      al[rt] = *reinterpret_cast<const short8*>((const char*)Al + byteoff);
    }
#pragma unroll
    for (int ct = 0; ct < 8; ++ct) {
      short8 bh = *reinterpret_cast<const short8*>(wph + (size_t)(ct * 16 + ks) * 512);
      short8 bl = *reinterpret_cast<const short8*>(wpl + (size_t)(ct * 16 + ks) * 512);
#pragma unroll
      for (int rt = 0; rt < 2; ++rt) {
        acc[rt][ct] = __builtin_amdgcn_mfma_f32_16x16x32_bf16(al[rt], bh, acc[rt][ct], 0, 0, 0);
        acc[rt][ct] = __builtin_amdgcn_mfma_f32_16x16x32_bf16(ah[rt], bl, acc[rt][ct], 0, 0, 0);
        acc[rt][ct] = __builtin_amdgcn_mfma_f32_16x16x32_bf16(ah[rt], bh, acc[rt][ct], 0, 0, 0);
      }
    }
  }

  __syncthreads();  // done reading A; reuse Ah as bf16 hn tile
  ushort_t* hn = Ah;
#pragma unroll
  for (int ct = 0; ct < 8; ++ct) {
    int n = w * 128 + ct * 16 + l15;
    float bias = bn1[b * D_DIM + n];
#pragma unroll
    for (int rt = 0; rt < 2; ++rt) {
#pragma unroll
      for (int j = 0; j < 4; ++j) {
        int row = rt * 16 + lq * 4 + j;
        float v = fmaxf(acc[rt][ct][j] + bias, 0.0f);
        unsigned bits = __float_as_uint(v);
        ushort_t hv = (ushort_t)((bits + 0x7fffu + ((bits >> 16) & 1u)) >> 16);
        int byteoff = row * 1024 + ((n * 2) ^ ((row & 7) << 4));
        *reinterpret_cast<ushort_t*>((char*)hn + byteoff) = hv;
      }
    }
  }
  __syncthreads();

  // second layer: waves 0,1 each handle one 16-row tile
  if (w < 2) {
    const int rt = w;
    f32x4 acc2 = (f32x4){0.f, 0.f, 0.f, 0.f};
    const ushort_t* __restrict__ w2 = W2T + (size_t)b * (16 * 512) + (size_t)l15 * 512 + lq * 8;
    const int R = rt * 16 + l15;
#pragma unroll
    for (int ks = 0; ks < 16; ++ks) {
      int byteoff = R * 1024 + ((ks * 64 + lq * 16) ^ ((R & 7) << 4));
      short8 a2 = *reinterpret_cast<const short8*>((const char*)hn + byteoff);
      short8 b2 = *reinterpret_cast<const short8*>(w2 + ks * 32);
      acc2 = __builtin_amdgcn_mfma_f32_16x16x32_bf16(a2, b2, acc2, 0, 0, 0);
    }
    int o = l15;
    if (o < 6) {
      float bo = bn2[b * 6 + o];
#pragma unroll
      for (int j = 0; j < 4; ++j) {
        int r = rt * 16 + lq * 4 + j;
        if (base + r < count) {
          int n = nidx[r];
          float v = acc2[j] + bo;
          if (o < NHD) out[NH_OFF + n * NHD + o] = v;
          else out[NV_OFF + n * NHD + (o - NHD)] = v * v;
        }
      }
    }
  }
}

// ---------------------------------------------------------------------------
// graph layer1: branch-grouped f32 tiles, 16 graphs x 96 cols per block
// ---------------------------------------------------------------------------
__global__ __launch_bounds__(256) void graph_l1_kernel(
    const float* __restrict__ xg, const float* __restrict__ Wg_shared,
    const float* __restrict__ bg_shared,
    const int* __restrict__ gcnt, const int* __restrict__ glist,
    float* __restrict__ hg) {
  __shared__ float As[16][16];
  __shared__ float Bs[16][96];
  __shared__ int gidx[16];
  const int bid = blockIdx.x;
  const int b = bid >> 9;
  const int t = bid & 511;
  const int tile = t >> 3, cb = t & 7;
  const int gc = gcnt[b];
  const int base = tile * 16;
  if (base >= gc) return;
  const int tid = threadIdx.x;
  const int tx = tid & 31, ty = tid >> 5;
  if (tid < 16) gidx[tid] = (base + tid < gc) ? glist[b * G_GRAPHS + base + tid] : glist[b * G_GRAPHS];
  float acc[2][3] = {{0.f, 0.f, 0.f}, {0.f, 0.f, 0.f}};
  const float* __restrict__ W1 = Wg_shared + (size_t)b * D_DIM * H_DIM + cb * 96;
  for (int k0 = 0; k0 < D_DIM; k0 += 16) {
    __syncthreads();
    if (tid < 64) {
      int r = tid >> 2, kq = tid & 3;
      float4 v = *reinterpret_cast<const float4*>(&xg[(size_t)gidx[r] * D_DIM + k0 + kq * 4]);
      As[kq * 4 + 0][r] = v.x; As[kq * 4 + 1][r] = v.y;
      As[kq * 4 + 2][r] = v.z; As[kq * 4 + 3][r] = v.w;
    }
    for (int e = tid; e < 16 * 24; e += 256) {
      int k = e / 24, c4 = e % 24;
      *reinterpret_cast<float4*>(&Bs[k][c4 * 4]) =
          *reinterpret_cast<const float4*>(&W1[(size_t)(k0 + k) * H_DIM + c4 * 4]);
    }
    __syncthreads();
#pragma unroll
    for (int k = 0; k < 16; ++k) {
      float a0 = As[k][ty * 2], a1 = As[k][ty * 2 + 1];
#pragma unroll
      for (int j = 0; j < 3; ++j) {
        float bv = Bs[k][tx + 32 * j];
        acc[0][j] += a0 * bv;
        acc[1][j] += a1 * bv;
      }
    }
  }
#pragma unroll
  for (int i = 0; i < 2; ++i) {
    int rr = ty * 2 + i;
    if (base + rr < gc) {
      int g = gidx[rr];
#pragma unroll
      for (int j = 0; j < 3; ++j) {
        int h = cb * 96 + tx + 32 * j;
        float v = fmaxf(acc[i][j] + bg_shared[b * H_DIM + h], 0.f);
        hg[(size_t)g * H_DIM + h] = v;
      }
    }
  }
}

// ---------------------------------------------------------------------------
// graph layer2: 8 graphs per block, hg staged in LDS
// ---------------------------------------------------------------------------
__global__ __launch_bounds__(256) void graph_l2_kernel(
    const float* __restrict__ hg, const float* __restrict__ Wg_head,
    const float* __restrict__ bg_head,
    const int* __restrict__ gcnt, const int* __restrict__ glist,
    float* __restrict__ out) {
  __shared__ float hs[8][H_DIM];
  __shared__ int gidx[8];
  const int b = blockIdx.x >> 7;
  const int tile = blockIdx.x & 127;
  const int gc = gcnt[b];
  if (tile * 8 >= gc) return;
  const int tid = threadIdx.x;
  if (tid < 8) gidx[tid] = (tile * 8 + tid < gc) ? glist[b * G_GRAPHS + tile * 8 + tid] : -1;
  __syncthreads();
  for (int e = tid; e < 8 * 192; e += 256) {
    int r = e / 192, c4 = e % 192;
    int g = gidx[r];
    float4 v = make_float4(0.f, 0.f, 0.f, 0.f);
    if (g >= 0) v = *reinterpret_cast<const float4*>(&hg[(size_t)g * H_DIM + c4 * 4]);
    *reinterpret_cast<float4*>(&hs[r][c4 * 4]) = v;
  }
  __syncthreads();
  const float* __restrict__ W2 = Wg_head + (size_t)b * H_DIM * 2 * GHD;
  const float* __restrict__ bh = bg_head + b * 2 * GHD;
#pragma unroll
  for (int it = 0; it < 4; ++it) {
    int idx = it * 256 + tid;
    int r = idx >> 7, o = idx & 127;
    int g = gidx[r];
    if (g < 0) continue;
    float s = bh[o];
#pragma unroll 4
    for (int h = 0; h < H_DIM; ++h) s += hs[r][h] * W2[(size_t)h * 2 * GHD + o];
    if (o < GHD) out[g * GHD + o] = s;
    else out[GV_OFF + g * GHD + (o - GHD)] = s * s;
  }
}

// ---------------------------------------------------------------------------
extern "C" void kernel_launch(void* const* d_in, const int* in_sizes, int n_in,
                              void* d_out, int out_size, void* d_ws, size_t ws_size,
                              hipStream_t stream) {
  const float* x         = (const float*)d_in[0];
  const int*   batch     = (const int*)d_in[1];
  const int*   dsname    = (const int*)d_in[2];
  const float* Wg_shared = (const float*)d_in[3];
  const float* bg_shared = (const float*)d_in[4];
  const float* Wg_head   = (const float*)d_in[5];
  const float* bg_head   = (const float*)d_in[6];
  const float* Wn1       = (const float*)d_in[7];
  const float* bn1       = (const float*)d_in[8];
  const float* Wn2       = (const float*)d_in[9];
  const float* bn2       = (const float*)d_in[10];
  float* out = (float*)d_out;

  int* ws_i   = (int*)d_ws;
  int* cnt    = ws_i;               // 4
  int* gcnt   = ws_i + 8;           // 4
  int* gstart = ws_i + 16;          // 1025
  int* goff   = ws_i + 1056;        // 1024
  int* glist  = ws_i + 2080;        // 4096
  int* lists  = ws_i + 6176;        // 4*32768
  float* xg   = (float*)(ws_i + 137248);   // 1024*512
  float* hg   = xg + 524288;               // 1024*768
  ushort_t* WPh = (ushort_t*)(hg + 786432);  // 4*512*512
  ushort_t* WPl = WPh + 1048576;
  ushort_t* W2T = WPl + 1048576;             // 4*16*512

  seg_kernel<<<5, 256, 0, stream>>>(batch, gstart);
  scan_kernel<<<1, 256, 0, stream>>>(dsname, gstart, goff, glist, cnt, gcnt);
  scatter_kernel<<<N_NODES / 256, 256, 0, stream>>>(batch, dsname, gstart, goff, lists);
  conv_w_kernel<<<256, 256, 0, stream>>>(Wn1, WPh, WPl);
  conv_w2_kernel<<<4, 256, 0, stream>>>(Wn2, W2T);
  pool_kernel<<<G_GRAPHS, 128, 0, stream>>>(x, gstart, xg);
  node_mfma_kernel<<<B_BR * (N_NODES / 32), 256, 0, stream>>>(
      x, WPh, WPl, bn1, W2T, bn2, cnt, lists, out);
  graph_l1_kernel<<<2048, 256, 0, stream>>>(xg, Wg_shared, bg_shared, gcnt, glist, hg);
  graph_l2_kernel<<<512, 256, 0, stream>>>(hg, Wg_head, bg_head, gcnt, glist, out);
}

// Round 5
// 284.570 us; speedup vs baseline: 3.0718x; 1.2425x over previous
//
#include <hip/hip_runtime.h>

#define N_NODES 32768
#define G_GRAPHS 1024
#define D_DIM 512
#define H_DIM 768
#define B_BR 4
#define GHD 64
#define NHD 3

// output layout (f32, concatenated flat)
#define NH_OFF (G_GRAPHS * GHD)
#define GV_OFF (G_GRAPHS * GHD + N_NODES * NHD)
#define NV_OFF (2 * G_GRAPHS * GHD + N_NODES * NHD)

typedef unsigned short ushort_t;
typedef __attribute__((ext_vector_type(8))) short short8;
typedef __attribute__((ext_vector_type(4))) float f32x4;
typedef __attribute__((ext_vector_type(4))) ushort_t ushort4_t;

__device__ __forceinline__ ushort_t rne_bf16(float v) {
  unsigned bits = __float_as_uint(v);
  return (ushort_t)((bits + 0x7fffu + ((bits >> 16) & 1u)) >> 16);
}

// ---------------------------------------------------------------------------
// per-graph segment bounds (batch is sorted)
// ---------------------------------------------------------------------------
__global__ __launch_bounds__(256) void seg_kernel(
    const int* __restrict__ batch, int* __restrict__ gstart) {
  int g = blockIdx.x * 256 + threadIdx.x;
  if (g > G_GRAPHS) return;
  if (g == G_GRAPHS) { gstart[G_GRAPHS] = N_NODES; return; }
  int lo = 0, hi = N_NODES;
  while (lo < hi) { int mid = (lo + hi) >> 1; if (batch[mid] < g) lo = mid + 1; else hi = mid; }
  gstart[g] = lo;
}

// ---------------------------------------------------------------------------
// 4-wave scan: wave b handles branch b. No atomics.
// ---------------------------------------------------------------------------
__global__ __launch_bounds__(256) void scan_kernel(
    const int* __restrict__ dsname, const int* __restrict__ gstart,
    int* __restrict__ goff, int* __restrict__ glist,
    int* __restrict__ cnt, int* __restrict__ gcnt) {
  const int lane = threadIdx.x & 63;
  const int b = threadIdx.x >> 6;
  int run_n = 0, run_g = 0;
  for (int c = 0; c < G_GRAPHS / 64; ++c) {
    int g = c * 64 + lane;
    int mine = (dsname[g] == b) ? 1 : 0;
    int len = mine ? (gstart[g + 1] - gstart[g]) : 0;
    int sl = len, so = mine;
#pragma unroll
    for (int off = 1; off < 64; off <<= 1) {
      int tl = __shfl_up(sl, off);
      int to = __shfl_up(so, off);
      if (lane >= off) { sl += tl; so += to; }
    }
    if (mine) {
      goff[g] = run_n + sl - len;
      glist[b * G_GRAPHS + run_g + so - 1] = g;
    }
    run_n += __shfl(sl, 63);
    run_g += __shfl(so, 63);
  }
  if (lane == 0) { cnt[b] = run_n; gcnt[b] = run_g; }
}

// ---------------------------------------------------------------------------
// scatter nodes into per-branch lists (atomic-free, ordered by node id)
// ---------------------------------------------------------------------------
__global__ __launch_bounds__(256) void scatter_kernel(
    const int* __restrict__ batch, const int* __restrict__ dsname,
    const int* __restrict__ gstart, const int* __restrict__ goff,
    int* __restrict__ lists) {
  int n = blockIdx.x * 256 + threadIdx.x;
  int g = batch[n];
  int b = dsname[g];
  lists[b * N_NODES + goff[g] + (n - gstart[g])] = n;
}

// ---------------------------------------------------------------------------
// Wn1 [b][k][n] f32 -> packed MFMA-fragment-order bf16 hi/lo:
// WP[b][n16][ks][lane][8], lane = lq*16+l15 holds (col n16*16+l15, k=ks*32+lq*8+j)
// ---------------------------------------------------------------------------
__global__ __launch_bounds__(256) void conv_w_kernel(
    const float* __restrict__ Wn1, ushort_t* __restrict__ WPh,
    ushort_t* __restrict__ WPl) {
  __shared__ float Ws[64][65];
  int b = blockIdx.x >> 6;
  int t = blockIdx.x & 63;
  int kt = t >> 3, nt = t & 7;
  const float* W = Wn1 + (size_t)b * D_DIM * D_DIM;
  for (int i = threadIdx.x; i < 64 * 64; i += 256) {
    int k = i >> 6, n = i & 63;
    Ws[k][n] = W[(size_t)(kt * 64 + k) * D_DIM + nt * 64 + n];
  }
  __syncthreads();
  for (int i = threadIdx.x; i < 64 * 8; i += 256) {
    int n = i >> 3, kq8 = i & 7;
    short8 sh, sl;
#pragma unroll
    for (int j = 0; j < 8; ++j) {
      float v = Ws[kq8 * 8 + j][n];
      unsigned bits = __float_as_uint(v);
      sh[j] = (short)(bits >> 16);
      float r = v - __uint_as_float(bits & 0xffff0000u);
      sl[j] = (short)(__float_as_uint(r) >> 16);
    }
    int gn = nt * 64 + n, gk0 = kt * 64 + kq8 * 8;
    int n16 = gn >> 4, l15 = gn & 15;
    int ks = gk0 >> 5, lq = (gk0 >> 3) & 3;
    size_t off = ((((size_t)b * 32 + n16) * 16 + ks) * 64 + lq * 16 + l15) * 8;
    *reinterpret_cast<short8*>(WPh + off) = sh;
    *reinterpret_cast<short8*>(WPl + off) = sl;
  }
}

// Wg_shared [b][k(512)][n(768)] f32 -> packed hi/lo [b][n16(48)][ks(16)][lane][8]
__global__ __launch_bounds__(256) void conv_wg1_kernel(
    const float* __restrict__ Wg, ushort_t* __restrict__ Gh,
    ushort_t* __restrict__ Gl) {
  __shared__ float Ws[64][65];
  int b = blockIdx.x / 96;
  int t = blockIdx.x % 96;
  int kt = t / 12, nt = t % 12;
  const float* W = Wg + (size_t)b * D_DIM * H_DIM;
  for (int i = threadIdx.x; i < 64 * 64; i += 256) {
    int k = i >> 6, n = i & 63;
    Ws[k][n] = W[(size_t)(kt * 64 + k) * H_DIM + nt * 64 + n];
  }
  __syncthreads();
  for (int i = threadIdx.x; i < 64 * 8; i += 256) {
    int n = i >> 3, kq8 = i & 7;
    short8 sh, sl;
#pragma unroll
    for (int j = 0; j < 8; ++j) {
      float v = Ws[kq8 * 8 + j][n];
      unsigned bits = __float_as_uint(v);
      sh[j] = (short)(bits >> 16);
      float r = v - __uint_as_float(bits & 0xffff0000u);
      sl[j] = (short)(__float_as_uint(r) >> 16);
    }
    int gn = nt * 64 + n, gk0 = kt * 64 + kq8 * 8;
    int n16 = gn >> 4, l15 = gn & 15;
    int ks = gk0 >> 5, lq = (gk0 >> 3) & 3;
    size_t off = ((((size_t)b * 48 + n16) * 16 + ks) * 64 + lq * 16 + l15) * 8;
    *reinterpret_cast<short8*>(Gh + off) = sh;
    *reinterpret_cast<short8*>(Gl + off) = sl;
  }
}

// Wg_head [b][k(768)][o(128)] f32 -> packed bf16 RNE [b][n16(8)][ks(24)][lane][8]
__global__ __launch_bounds__(256) void conv_wg2_kernel(
    const float* __restrict__ Wh, ushort_t* __restrict__ G2) {
  int b = blockIdx.x;
  const float* W = Wh + (size_t)b * H_DIM * 2 * GHD;
  for (int i = threadIdx.x; i < 8 * 24 * 64; i += 256) {
    int n16 = i / (24 * 64);
    int rem = i % (24 * 64);
    int ks = rem / 64, lane = rem % 64;
    int l15 = lane & 15, lq = lane >> 4;
    int o = n16 * 16 + l15;
    short8 sv;
#pragma unroll
    for (int j = 0; j < 8; ++j) {
      int k = ks * 32 + lq * 8 + j;
      sv[j] = (short)rne_bf16(W[(size_t)k * 128 + o]);
    }
    *reinterpret_cast<short8*>(G2 + (size_t)i * 8 + (size_t)b * (8 * 24 * 64 * 8)) = sv;
  }
}

// Wn2 [b][c][o] (o<6) -> W2T [b][o][c], o padded to 16 with zeros, bf16 RNE
__global__ __launch_bounds__(256) void conv_w2_kernel(
    const float* __restrict__ Wn2, ushort_t* __restrict__ W2T) {
  int b = blockIdx.x;
  for (int i = threadIdx.x; i < 16 * D_DIM; i += 256) {
    int o = i & 15, c = i >> 4;
    float v = (o < 6) ? Wn2[(size_t)b * D_DIM * 6 + c * 6 + o] : 0.0f;
    W2T[(size_t)b * 16 * D_DIM + o * D_DIM + c] = rne_bf16(v);
  }
}

// ---------------------------------------------------------------------------
// mean-pool per graph -> xg[1024][512] f32
// ---------------------------------------------------------------------------
__global__ __launch_bounds__(128) void pool_kernel(
    const float* __restrict__ x, const int* __restrict__ gstart,
    float* __restrict__ xg) {
  const int g = blockIdx.x;
  const int tid = threadIdx.x;
  const int start = gstart[g], end = gstart[g + 1];
  const float inv = (end > start) ? 1.0f / (float)(end - start) : 0.0f;
  float4 acc = make_float4(0.f, 0.f, 0.f, 0.f);
  for (int i = start; i < end; ++i) {
    float4 v = *reinterpret_cast<const float4*>(&x[(size_t)i * D_DIM + tid * 4]);
    acc.x += v.x; acc.y += v.y; acc.z += v.z; acc.w += v.w;
  }
  acc.x *= inv; acc.y *= inv; acc.z *= inv; acc.w *= inv;
  *reinterpret_cast<float4*>(&xg[(size_t)g * D_DIM + tid * 4]) = acc;
}

// ---------------------------------------------------------------------------
// node path: MFMA grouped GEMM, 32 gathered rows x 512 cols per block.
// ---------------------------------------------------------------------------
__global__ __launch_bounds__(256) void node_mfma_kernel(
    const float* __restrict__ x,
    const ushort_t* __restrict__ WPh, const ushort_t* __restrict__ WPl,
    const float* __restrict__ bn1,
    const ushort_t* __restrict__ W2T, const float* __restrict__ bn2,
    const int* __restrict__ cnt, const int* __restrict__ lists,
    float* __restrict__ out) {
  __shared__ ushort_t Ah[32 * 512];
  __shared__ ushort_t Al[32 * 512];
  __shared__ int nidx[32];

  const int tile = blockIdx.x & 1023;
  const int b = blockIdx.x >> 10;
  const int count = cnt[b];
  const int base = tile * 32;
  if (base >= count) return;

  const int tid = threadIdx.x;
  const int lane = tid & 63;
  const int w = tid >> 6;
  const int l15 = lane & 15;
  const int lq = lane >> 4;

  if (tid < 32) {
    int r = base + tid;
    nidx[tid] = (r < count) ? lists[b * N_NODES + r] : lists[b * N_NODES];
  }
  __syncthreads();

#pragma unroll
  for (int it = 0; it < 16; ++it) {
    int u = it * 256 + tid;
    int r = u >> 7, c4 = u & 127;
    float4 v = *reinterpret_cast<const float4*>(&x[(size_t)nidx[r] * D_DIM + c4 * 4]);
    float fv[4] = {v.x, v.y, v.z, v.w};
    ushort4_t h4, l4;
#pragma unroll
    for (int j = 0; j < 4; ++j) {
      unsigned bits = __float_as_uint(fv[j]);
      h4[j] = (ushort_t)(bits >> 16);
      float rr = fv[j] - __uint_as_float(bits & 0xffff0000u);
      l4[j] = (ushort_t)(__float_as_uint(rr) >> 16);
    }
    int byteoff = r * 1024 + ((c4 * 8) ^ ((r & 7) << 4));
    *reinterpret_cast<ushort4_t*>((char*)Ah + byteoff) = h4;
    *reinterpret_cast<ushort4_t*>((char*)Al + byteoff) = l4;
  }
  __syncthreads();

  f32x4 acc[2][8];
#pragma unroll
  for (int i = 0; i < 2; ++i)
#pragma unroll
    for (int j = 0; j < 8; ++j) acc[i][j] = (f32x4){0.f, 0.f, 0.f, 0.f};

  const size_t wpo = (((size_t)b * 32 + w * 8) * 16) * 512 + (size_t)lane * 8;
  const ushort_t* __restrict__ wph = WPh + wpo;
  const ushort_t* __restrict__ wpl = WPl + wpo;

  for (int ks = 0; ks < 16; ++ks) {
    short8 ah[2], al[2];
#pragma unroll
    for (int rt = 0; rt < 2; ++rt) {
      int R = rt * 16 + l15;
      int byteoff = R * 1024 + ((ks * 64 + lq * 16) ^ ((R & 7) << 4));
      ah[rt] = *reinterpret_cast<const short8*>((const char*)Ah + byteoff);
      al[rt] = *reinterpret_cast<const short8*>((const char*)Al + byteoff);
    }
#pragma unroll
    for (int ct = 0; ct < 8; ++ct) {
      short8 bh = *reinterpret_cast<const short8*>(wph + (size_t)(ct * 16 + ks) * 512);
      short8 bl = *reinterpret_cast<const short8*>(wpl + (size_t)(ct * 16 + ks) * 512);
#pragma unroll
      for (int rt = 0; rt < 2; ++rt) {
        acc[rt][ct] = __builtin_amdgcn_mfma_f32_16x16x32_bf16(al[rt], bh, acc[rt][ct], 0, 0, 0);
        acc[rt][ct] = __builtin_amdgcn_mfma_f32_16x16x32_bf16(ah[rt], bl, acc[rt][ct], 0, 0, 0);
        acc[rt][ct] = __builtin_amdgcn_mfma_f32_16x16x32_bf16(ah[rt], bh, acc[rt][ct], 0, 0, 0);
      }
    }
  }

  __syncthreads();
  ushort_t* hn = Ah;
#pragma unroll
  for (int ct = 0; ct < 8; ++ct) {
    int n = w * 128 + ct * 16 + l15;
    float bias = bn1[b * D_DIM + n];
#pragma unroll
    for (int rt = 0; rt < 2; ++rt) {
#pragma unroll
      for (int j = 0; j < 4; ++j) {
        int row = rt * 16 + lq * 4 + j;
        float v = fmaxf(acc[rt][ct][j] + bias, 0.0f);
        int byteoff = row * 1024 + ((n * 2) ^ ((row & 7) << 4));
        *reinterpret_cast<ushort_t*>((char*)hn + byteoff) = rne_bf16(v);
      }
    }
  }
  __syncthreads();

  if (w < 2) {
    const int rt = w;
    f32x4 acc2 = (f32x4){0.f, 0.f, 0.f, 0.f};
    const ushort_t* __restrict__ w2 = W2T + (size_t)b * (16 * 512) + (size_t)l15 * 512 + lq * 8;
    const int R = rt * 16 + l15;
#pragma unroll
    for (int ks = 0; ks < 16; ++ks) {
      int byteoff = R * 1024 + ((ks * 64 + lq * 16) ^ ((R & 7) << 4));
      short8 a2 = *reinterpret_cast<const short8*>((const char*)hn + byteoff);
      short8 b2 = *reinterpret_cast<const short8*>(w2 + ks * 32);
      acc2 = __builtin_amdgcn_mfma_f32_16x16x32_bf16(a2, b2, acc2, 0, 0, 0);
    }
    int o = l15;
    if (o < 6) {
      float bo = bn2[b * 6 + o];
#pragma unroll
      for (int j = 0; j < 4; ++j) {
        int r = rt * 16 + lq * 4 + j;
        if (base + r < count) {
          int n = nidx[r];
          float v = acc2[j] + bo;
          if (o < NHD) out[NH_OFF + n * NHD + o] = v;
          else out[NV_OFF + n * NHD + (o - NHD)] = v * v;
        }
      }
    }
  }
}

// ---------------------------------------------------------------------------
// fused graph path: per block = 32 branch-grouped graphs.
// L1: xg(hi/lo LDS) @ WG1(hi/lo packed) -> relu -> bf16 hg in LDS
// L2: hg @ WG2(packed bf16) -> graph_head / graph_var
// ---------------------------------------------------------------------------
__global__ __launch_bounds__(256) void graph_fused_kernel(
    const float* __restrict__ xg,
    const ushort_t* __restrict__ WG1h, const ushort_t* __restrict__ WG1l,
    const float* __restrict__ bg_shared,
    const ushort_t* __restrict__ WG2, const float* __restrict__ bg_head,
    const int* __restrict__ gcnt, const int* __restrict__ glist,
    float* __restrict__ out) {
  __shared__ __align__(16) char gbuf[65536];  // phase1: Ah(32K)+Al(32K); phase2: hg 32x768 bf16 (48K)
  __shared__ int gidx[32];
  ushort_t* Ah = (ushort_t*)gbuf;
  ushort_t* Al = (ushort_t*)(gbuf + 32768);

  const int b = blockIdx.x >> 5;
  const int tile = blockIdx.x & 31;
  const int gc = gcnt[b];
  const int base = tile * 32;
  if (base >= gc) return;

  const int tid = threadIdx.x;
  const int lane = tid & 63;
  const int w = tid >> 6;
  const int l15 = lane & 15;
  const int lq = lane >> 4;

  if (tid < 32) {
    int r = base + tid;
    gidx[tid] = (r < gc) ? glist[b * G_GRAPHS + r] : glist[b * G_GRAPHS];
  }
  __syncthreads();

  // stage xg rows as bf16 hi/lo, swizzled
#pragma unroll
  for (int it = 0; it < 16; ++it) {
    int u = it * 256 + tid;
    int r = u >> 7, c4 = u & 127;
    float4 v = *reinterpret_cast<const float4*>(&xg[(size_t)gidx[r] * D_DIM + c4 * 4]);
    float fv[4] = {v.x, v.y, v.z, v.w};
    ushort4_t h4, l4;
#pragma unroll
    for (int j = 0; j < 4; ++j) {
      unsigned bits = __float_as_uint(fv[j]);
      h4[j] = (ushort_t)(bits >> 16);
      float rr = fv[j] - __uint_as_float(bits & 0xffff0000u);
      l4[j] = (ushort_t)(__float_as_uint(rr) >> 16);
    }
    int byteoff = r * 1024 + ((c4 * 8) ^ ((r & 7) << 4));
    *reinterpret_cast<ushort4_t*>((char*)Ah + byteoff) = h4;
    *reinterpret_cast<ushort4_t*>((char*)Al + byteoff) = l4;
  }
  __syncthreads();

  // L1: each wave covers 12 col-tiles (192 cols)
  f32x4 acc[2][12];
#pragma unroll
  for (int i = 0; i < 2; ++i)
#pragma unroll
    for (int j = 0; j < 12; ++j) acc[i][j] = (f32x4){0.f, 0.f, 0.f, 0.f};

  const size_t g1o = (((size_t)b * 48 + w * 12) * 16) * 512 + (size_t)lane * 8;
  const ushort_t* __restrict__ g1h = WG1h + g1o;
  const ushort_t* __restrict__ g1l = WG1l + g1o;

  for (int ks = 0; ks < 16; ++ks) {
    short8 ah[2], al[2];
#pragma unroll
    for (int rt = 0; rt < 2; ++rt) {
      int R = rt * 16 + l15;
      int byteoff = R * 1024 + ((ks * 64 + lq * 16) ^ ((R & 7) << 4));
      ah[rt] = *reinterpret_cast<const short8*>((const char*)Ah + byteoff);
      al[rt] = *reinterpret_cast<const short8*>((const char*)Al + byteoff);
    }
#pragma unroll
    for (int ct = 0; ct < 12; ++ct) {
      short8 bh = *reinterpret_cast<const short8*>(g1h + (size_t)(ct * 16 + ks) * 512);
      short8 bl = *reinterpret_cast<const short8*>(g1l + (size_t)(ct * 16 + ks) * 512);
#pragma unroll
      for (int rt = 0; rt < 2; ++rt) {
        acc[rt][ct] = __builtin_amdgcn_mfma_f32_16x16x32_bf16(al[rt], bh, acc[rt][ct], 0, 0, 0);
        acc[rt][ct] = __builtin_amdgcn_mfma_f32_16x16x32_bf16(ah[rt], bl, acc[rt][ct], 0, 0, 0);
        acc[rt][ct] = __builtin_amdgcn_mfma_f32_16x16x32_bf16(ah[rt], bh, acc[rt][ct], 0, 0, 0);
      }
    }
  }

  __syncthreads();  // done reading Ah/Al; reuse gbuf as hg (32 x 768 bf16, row stride 1536B)
  ushort_t* hgs = (ushort_t*)gbuf;
#pragma unroll
  for (int ct = 0; ct < 12; ++ct) {
    int n = w * 192 + ct * 16 + l15;
    float bias = bg_shared[b * H_DIM + n];
#pragma unroll
    for (int rt = 0; rt < 2; ++rt) {
#pragma unroll
      for (int j = 0; j < 4; ++j) {
        int row = rt * 16 + lq * 4 + j;
        float v = fmaxf(acc[rt][ct][j] + bias, 0.0f);
        int byteoff = row * 1536 + ((n * 2) ^ ((row & 7) << 4));
        *reinterpret_cast<ushort_t*>((char*)hgs + byteoff) = rne_bf16(v);
      }
    }
  }
  __syncthreads();

  // L2: 32x128, K=768. wave w covers o-tiles w*2, w*2+1
  f32x4 acc2[2][2];
#pragma unroll
  for (int i = 0; i < 2; ++i)
#pragma unroll
    for (int j = 0; j < 2; ++j) acc2[i][j] = (f32x4){0.f, 0.f, 0.f, 0.f};

  const ushort_t* __restrict__ g2 = WG2 + ((size_t)(b * 8 + w * 2) * 24 * 64 + lane) * 8;

  for (int ks = 0; ks < 24; ++ks) {
    short8 a2[2];
#pragma unroll
    for (int rt = 0; rt < 2; ++rt) {
      int R = rt * 16 + l15;
      int byteoff = R * 1536 + ((ks * 64 + lq * 16) ^ ((R & 7) << 4));
      a2[rt] = *reinterpret_cast<const short8*>((const char*)hgs + byteoff);
    }
#pragma unroll
    for (int ct = 0; ct < 2; ++ct) {
      short8 b2 = *reinterpret_cast<const short8*>(g2 + (size_t)ct * 12288 + (size_t)ks * 512);
#pragma unroll
      for (int rt = 0; rt < 2; ++rt) {
        acc2[rt][ct] = __builtin_amdgcn_mfma_f32_16x16x32_bf16(a2[rt], b2, acc2[rt][ct], 0, 0, 0);
      }
    }
  }

#pragma unroll
  for (int ct = 0; ct < 2; ++ct) {
    int o = (w * 2 + ct) * 16 + l15;
    float bo = bg_head[b * 2 * GHD + o];
#pragma unroll
    for (int rt = 0; rt < 2; ++rt) {
#pragma unroll
      for (int j = 0; j < 4; ++j) {
        int r = rt * 16 + lq * 4 + j;
        if (base + r < gc) {
          int g = gidx[r];
          float v = acc2[rt][ct][j] + bo;
          if (o < GHD) out[g * GHD + o] = v;
          else out[GV_OFF + g * GHD + (o - GHD)] = v * v;
        }
      }
    }
  }
}

// ---------------------------------------------------------------------------
extern "C" void kernel_launch(void* const* d_in, const int* in_sizes, int n_in,
                              void* d_out, int out_size, void* d_ws, size_t ws_size,
                              hipStream_t stream) {
  const float* x         = (const float*)d_in[0];
  const int*   batch     = (const int*)d_in[1];
  const int*   dsname    = (const int*)d_in[2];
  const float* Wg_shared = (const float*)d_in[3];
  const float* bg_shared = (const float*)d_in[4];
  const float* Wg_head   = (const float*)d_in[5];
  const float* bg_head   = (const float*)d_in[6];
  const float* Wn1       = (const float*)d_in[7];
  const float* bn1       = (const float*)d_in[8];
  const float* Wn2       = (const float*)d_in[9];
  const float* bn2       = (const float*)d_in[10];
  float* out = (float*)d_out;

  int* ws_i   = (int*)d_ws;
  int* cnt    = ws_i;               // 4
  int* gcnt   = ws_i + 8;           // 4
  int* gstart = ws_i + 16;          // 1025
  int* goff   = ws_i + 1056;        // 1024
  int* glist  = ws_i + 2080;        // 4096
  int* lists  = ws_i + 6176;        // 4*32768 -> end 137248
  float* xg   = (float*)(ws_i + 137248);     // 1024*512 f32
  ushort_t* WPh  = (ushort_t*)(xg + 524288); // 4*512*512
  ushort_t* WPl  = WPh + 1048576;
  ushort_t* W2T  = WPl + 1048576;            // 4*16*512 = 32768
  ushort_t* WG1h = W2T + 32768;              // 4*48*16*64*8 = 1572864
  ushort_t* WG1l = WG1h + 1572864;
  ushort_t* WG2  = WG1l + 1572864;           // 4*8*24*64*8 = 393216

  seg_kernel<<<5, 256, 0, stream>>>(batch, gstart);
  scan_kernel<<<1, 256, 0, stream>>>(dsname, gstart, goff, glist, cnt, gcnt);
  scatter_kernel<<<N_NODES / 256, 256, 0, stream>>>(batch, dsname, gstart, goff, lists);
  conv_w_kernel<<<256, 256, 0, stream>>>(Wn1, WPh, WPl);
  conv_w2_kernel<<<4, 256, 0, stream>>>(Wn2, W2T);
  conv_wg1_kernel<<<384, 256, 0, stream>>>(Wg_shared, WG1h, WG1l);
  conv_wg2_kernel<<<4, 256, 0, stream>>>(Wg_head, WG2);
  pool_kernel<<<G_GRAPHS, 128, 0, stream>>>(x, gstart, xg);
  node_mfma_kernel<<<B_BR * (N_NODES / 32), 256, 0, stream>>>(
      x, WPh, WPl, bn1, W2T, bn2, cnt, lists, out);
  graph_fused_kernel<<<B_BR * 32, 256, 0, stream>>>(
      xg, WG1h, WG1l, bg_shared, WG2, bg_head, gcnt, glist, out);
}

// Round 6
// 224.519 us; speedup vs baseline: 3.8934x; 1.2675x over previous
//
#include <hip/hip_runtime.h>

#define N_NODES 32768
#define G_GRAPHS 1024
#define D_DIM 512
#define H_DIM 768
#define B_BR 4
#define GHD 64
#define NHD 3

// output layout (f32, concatenated flat)
#define NH_OFF (G_GRAPHS * GHD)
#define GV_OFF (G_GRAPHS * GHD + N_NODES * NHD)
#define NV_OFF (2 * G_GRAPHS * GHD + N_NODES * NHD)

typedef unsigned short ushort_t;
typedef __attribute__((ext_vector_type(8))) short short8;
typedef __attribute__((ext_vector_type(4))) float f32x4;
typedef __attribute__((ext_vector_type(4))) ushort_t ushort4_t;

__device__ __forceinline__ ushort_t rne_bf16(float v) {
  unsigned bits = __float_as_uint(v);
  return (ushort_t)((bits + 0x7fffu + ((bits >> 16) & 1u)) >> 16);
}

// ---------------------------------------------------------------------------
// per-graph segment bounds (batch is sorted)
// ---------------------------------------------------------------------------
__global__ __launch_bounds__(256) void seg_kernel(
    const int* __restrict__ batch, int* __restrict__ gstart) {
  int g = blockIdx.x * 256 + threadIdx.x;
  if (g > G_GRAPHS) return;
  if (g == G_GRAPHS) { gstart[G_GRAPHS] = N_NODES; return; }
  int lo = 0, hi = N_NODES;
  while (lo < hi) { int mid = (lo + hi) >> 1; if (batch[mid] < g) lo = mid + 1; else hi = mid; }
  gstart[g] = lo;
}

// ---------------------------------------------------------------------------
// 4-wave scan: wave b handles branch b. No atomics.
// ---------------------------------------------------------------------------
__global__ __launch_bounds__(256) void scan_kernel(
    const int* __restrict__ dsname, const int* __restrict__ gstart,
    int* __restrict__ goff, int* __restrict__ glist,
    int* __restrict__ cnt, int* __restrict__ gcnt) {
  const int lane = threadIdx.x & 63;
  const int b = threadIdx.x >> 6;
  int run_n = 0, run_g = 0;
  for (int c = 0; c < G_GRAPHS / 64; ++c) {
    int g = c * 64 + lane;
    int mine = (dsname[g] == b) ? 1 : 0;
    int len = mine ? (gstart[g + 1] - gstart[g]) : 0;
    int sl = len, so = mine;
#pragma unroll
    for (int off = 1; off < 64; off <<= 1) {
      int tl = __shfl_up(sl, off);
      int to = __shfl_up(so, off);
      if (lane >= off) { sl += tl; so += to; }
    }
    if (mine) {
      goff[g] = run_n + sl - len;
      glist[b * G_GRAPHS + run_g + so - 1] = g;
    }
    run_n += __shfl(sl, 63);
    run_g += __shfl(so, 63);
  }
  if (lane == 0) { cnt[b] = run_n; gcnt[b] = run_g; }
}

// ---------------------------------------------------------------------------
// scatter nodes into per-branch lists (atomic-free, ordered by node id)
// ---------------------------------------------------------------------------
__global__ __launch_bounds__(256) void scatter_kernel(
    const int* __restrict__ batch, const int* __restrict__ dsname,
    const int* __restrict__ gstart, const int* __restrict__ goff,
    int* __restrict__ lists) {
  int n = blockIdx.x * 256 + threadIdx.x;
  int g = batch[n];
  int b = dsname[g];
  lists[b * N_NODES + goff[g] + (n - gstart[g])] = n;
}

// ---------------------------------------------------------------------------
// Wn1 [b][k][n] f32 -> packed MFMA-fragment-order bf16 (RNE):
// WP[b][n16][ks][lane][8], lane = lq*16+l15 holds (col n16*16+l15, k=ks*32+lq*8+j)
// ---------------------------------------------------------------------------
__global__ __launch_bounds__(256) void conv_w_kernel(
    const float* __restrict__ Wn1, ushort_t* __restrict__ WPh) {
  __shared__ float Ws[64][65];
  int b = blockIdx.x >> 6;
  int t = blockIdx.x & 63;
  int kt = t >> 3, nt = t & 7;
  const float* W = Wn1 + (size_t)b * D_DIM * D_DIM;
  for (int i = threadIdx.x; i < 64 * 64; i += 256) {
    int k = i >> 6, n = i & 63;
    Ws[k][n] = W[(size_t)(kt * 64 + k) * D_DIM + nt * 64 + n];
  }
  __syncthreads();
  for (int i = threadIdx.x; i < 64 * 8; i += 256) {
    int n = i >> 3, kq8 = i & 7;
    short8 sh;
#pragma unroll
    for (int j = 0; j < 8; ++j) sh[j] = (short)rne_bf16(Ws[kq8 * 8 + j][n]);
    int gn = nt * 64 + n, gk0 = kt * 64 + kq8 * 8;
    int n16 = gn >> 4, l15 = gn & 15;
    int ks = gk0 >> 5, lq = (gk0 >> 3) & 3;
    size_t off = ((((size_t)b * 32 + n16) * 16 + ks) * 64 + lq * 16 + l15) * 8;
    *reinterpret_cast<short8*>(WPh + off) = sh;
  }
}

// Wg_shared [b][k(512)][n(768)] f32 -> packed bf16 RNE [b][n16(48)][ks(16)][lane][8]
__global__ __launch_bounds__(256) void conv_wg1_kernel(
    const float* __restrict__ Wg, ushort_t* __restrict__ Gh) {
  __shared__ float Ws[64][65];
  int b = blockIdx.x / 96;
  int t = blockIdx.x % 96;
  int kt = t / 12, nt = t % 12;
  const float* W = Wg + (size_t)b * D_DIM * H_DIM;
  for (int i = threadIdx.x; i < 64 * 64; i += 256) {
    int k = i >> 6, n = i & 63;
    Ws[k][n] = W[(size_t)(kt * 64 + k) * H_DIM + nt * 64 + n];
  }
  __syncthreads();
  for (int i = threadIdx.x; i < 64 * 8; i += 256) {
    int n = i >> 3, kq8 = i & 7;
    short8 sh;
#pragma unroll
    for (int j = 0; j < 8; ++j) sh[j] = (short)rne_bf16(Ws[kq8 * 8 + j][n]);
    int gn = nt * 64 + n, gk0 = kt * 64 + kq8 * 8;
    int n16 = gn >> 4, l15 = gn & 15;
    int ks = gk0 >> 5, lq = (gk0 >> 3) & 3;
    size_t off = ((((size_t)b * 48 + n16) * 16 + ks) * 64 + lq * 16 + l15) * 8;
    *reinterpret_cast<short8*>(Gh + off) = sh;
  }
}

// Wg_head [b][k(768)][o(128)] f32 -> packed bf16 RNE [b][n16(8)][ks(24)][lane][8]
__global__ __launch_bounds__(256) void conv_wg2_kernel(
    const float* __restrict__ Wh, ushort_t* __restrict__ G2) {
  int b = blockIdx.x;
  const float* W = Wh + (size_t)b * H_DIM * 2 * GHD;
  for (int i = threadIdx.x; i < 8 * 24 * 64; i += 256) {
    int n16 = i / (24 * 64);
    int rem = i % (24 * 64);
    int ks = rem / 64, lane = rem % 64;
    int l15 = lane & 15, lq = lane >> 4;
    int o = n16 * 16 + l15;
    short8 sv;
#pragma unroll
    for (int j = 0; j < 8; ++j) {
      int k = ks * 32 + lq * 8 + j;
      sv[j] = (short)rne_bf16(W[(size_t)k * 128 + o]);
    }
    *reinterpret_cast<short8*>(G2 + (size_t)i * 8 + (size_t)b * (8 * 24 * 64 * 8)) = sv;
  }
}

// Wn2 [b][c][o] (o<6) -> W2T [b][o][c], o padded to 16 with zeros, bf16 RNE
__global__ __launch_bounds__(256) void conv_w2_kernel(
    const float* __restrict__ Wn2, ushort_t* __restrict__ W2T) {
  int b = blockIdx.x;
  for (int i = threadIdx.x; i < 16 * D_DIM; i += 256) {
    int o = i & 15, c = i >> 4;
    float v = (o < 6) ? Wn2[(size_t)b * D_DIM * 6 + c * 6 + o] : 0.0f;
    W2T[(size_t)b * 16 * D_DIM + o * D_DIM + c] = rne_bf16(v);
  }
}

// ---------------------------------------------------------------------------
// mean-pool per graph -> xg[1024][512] f32
// ---------------------------------------------------------------------------
__global__ __launch_bounds__(128) void pool_kernel(
    const float* __restrict__ x, const int* __restrict__ gstart,
    float* __restrict__ xg) {
  const int g = blockIdx.x;
  const int tid = threadIdx.x;
  const int start = gstart[g], end = gstart[g + 1];
  const float inv = (end > start) ? 1.0f / (float)(end - start) : 0.0f;
  float4 acc = make_float4(0.f, 0.f, 0.f, 0.f);
  for (int i = start; i < end; ++i) {
    float4 v = *reinterpret_cast<const float4*>(&x[(size_t)i * D_DIM + tid * 4]);
    acc.x += v.x; acc.y += v.y; acc.z += v.z; acc.w += v.w;
  }
  acc.x *= inv; acc.y *= inv; acc.z *= inv; acc.w *= inv;
  *reinterpret_cast<float4*>(&xg[(size_t)g * D_DIM + tid * 4]) = acc;
}

// ---------------------------------------------------------------------------
// node path: MFMA grouped GEMM, BM=64 gathered rows x 512 cols per block.
// A staged as single RNE bf16 in LDS (XOR-swizzled), B single bf16 packed.
// Layer2 (512->6) fused: one MFMA per 16-row tile, one tile per wave.
// ---------------------------------------------------------------------------
#define NBM 64

__global__ __launch_bounds__(256) void node_mfma_kernel(
    const float* __restrict__ x,
    const ushort_t* __restrict__ WPh,
    const float* __restrict__ bn1,
    const ushort_t* __restrict__ W2T, const float* __restrict__ bn2,
    const int* __restrict__ cnt, const int* __restrict__ lists,
    float* __restrict__ out) {
  __shared__ ushort_t Ah[NBM * 512];  // 64 KB
  __shared__ int nidx[NBM];

  const int tile = blockIdx.x & 511;
  const int b = blockIdx.x >> 9;
  const int count = cnt[b];
  const int base = tile * NBM;
  if (base >= count) return;

  const int tid = threadIdx.x;
  const int lane = tid & 63;
  const int w = tid >> 6;
  const int l15 = lane & 15;
  const int lq = lane >> 4;

  if (tid < NBM) {
    int r = base + tid;
    nidx[tid] = (r < count) ? lists[b * N_NODES + r] : lists[b * N_NODES];
  }
  __syncthreads();

  // stage A: 64 rows x 128 float4-chunks = 8192 units over 32 iters
#pragma unroll
  for (int it = 0; it < 32; ++it) {
    int u = it * 256 + tid;
    int r = u >> 7, c4 = u & 127;
    float4 v = *reinterpret_cast<const float4*>(&x[(size_t)nidx[r] * D_DIM + c4 * 4]);
    ushort4_t h4;
    h4[0] = rne_bf16(v.x); h4[1] = rne_bf16(v.y);
    h4[2] = rne_bf16(v.z); h4[3] = rne_bf16(v.w);
    int byteoff = r * 1024 + ((c4 * 8) ^ ((r & 7) << 4));
    *reinterpret_cast<ushort4_t*>((char*)Ah + byteoff) = h4;
  }
  __syncthreads();

  f32x4 acc[4][8];
#pragma unroll
  for (int i = 0; i < 4; ++i)
#pragma unroll
    for (int j = 0; j < 8; ++j) acc[i][j] = (f32x4){0.f, 0.f, 0.f, 0.f};

  const ushort_t* __restrict__ wph =
      WPh + (((size_t)b * 32 + w * 8) * 16) * 512 + (size_t)lane * 8;

  for (int ks = 0; ks < 16; ++ks) {
    short8 ah[4];
#pragma unroll
    for (int rt = 0; rt < 4; ++rt) {
      int R = rt * 16 + l15;
      int byteoff = R * 1024 + ((ks * 64 + lq * 16) ^ ((R & 7) << 4));
      ah[rt] = *reinterpret_cast<const short8*>((const char*)Ah + byteoff);
    }
#pragma unroll
    for (int ct = 0; ct < 8; ++ct) {
      short8 bh = *reinterpret_cast<const short8*>(wph + (size_t)(ct * 16 + ks) * 512);
#pragma unroll
      for (int rt = 0; rt < 4; ++rt) {
        acc[rt][ct] = __builtin_amdgcn_mfma_f32_16x16x32_bf16(ah[rt], bh, acc[rt][ct], 0, 0, 0);
      }
    }
  }

  __syncthreads();  // done reading A; reuse Ah as bf16 hn tile (64 x 512)
  ushort_t* hn = Ah;
#pragma unroll
  for (int ct = 0; ct < 8; ++ct) {
    int n = w * 128 + ct * 16 + l15;
    float bias = bn1[b * D_DIM + n];
#pragma unroll
    for (int rt = 0; rt < 4; ++rt) {
#pragma unroll
      for (int j = 0; j < 4; ++j) {
        int row = rt * 16 + lq * 4 + j;
        float v = fmaxf(acc[rt][ct][j] + bias, 0.0f);
        int byteoff = row * 1024 + ((n * 2) ^ ((row & 7) << 4));
        *reinterpret_cast<ushort_t*>((char*)hn + byteoff) = rne_bf16(v);
      }
    }
  }
  __syncthreads();

  // second layer: wave w handles row-tile w (rows w*16 .. w*16+15)
  {
    f32x4 acc2 = (f32x4){0.f, 0.f, 0.f, 0.f};
    const ushort_t* __restrict__ w2 = W2T + (size_t)b * (16 * 512) + (size_t)l15 * 512 + lq * 8;
    const int R = w * 16 + l15;
#pragma unroll
    for (int ks = 0; ks < 16; ++ks) {
      int byteoff = R * 1024 + ((ks * 64 + lq * 16) ^ ((R & 7) << 4));
      short8 a2 = *reinterpret_cast<const short8*>((const char*)hn + byteoff);
      short8 b2 = *reinterpret_cast<const short8*>(w2 + ks * 32);
      acc2 = __builtin_amdgcn_mfma_f32_16x16x32_bf16(a2, b2, acc2, 0, 0, 0);
    }
    int o = l15;
    if (o < 6) {
      float bo = bn2[b * 6 + o];
#pragma unroll
      for (int j = 0; j < 4; ++j) {
        int r = w * 16 + lq * 4 + j;
        if (base + r < count) {
          int n = nidx[r];
          float v = acc2[j] + bo;
          if (o < NHD) out[NH_OFF + n * NHD + o] = v;
          else out[NV_OFF + n * NHD + (o - NHD)] = v * v;
        }
      }
    }
  }
}

// ---------------------------------------------------------------------------
// fused graph path: per block = 32 branch-grouped graphs, full bf16.
// L1: xg(bf16 LDS) @ WG1(packed bf16) -> relu -> bf16 hg in LDS
// L2: hg @ WG2(packed bf16) -> graph_head / graph_var
// ---------------------------------------------------------------------------
__global__ __launch_bounds__(256) void graph_fused_kernel(
    const float* __restrict__ xg,
    const ushort_t* __restrict__ WG1h,
    const float* __restrict__ bg_shared,
    const ushort_t* __restrict__ WG2, const float* __restrict__ bg_head,
    const int* __restrict__ gcnt, const int* __restrict__ glist,
    float* __restrict__ out) {
  __shared__ __align__(16) char gbuf[49152];  // phase1: xa 32x512 bf16 (32K); phase2: hg 32x768 bf16 (48K)
  __shared__ int gidx[32];
  ushort_t* Ah = (ushort_t*)gbuf;

  const int b = blockIdx.x >> 5;
  const int tile = blockIdx.x & 31;
  const int gc = gcnt[b];
  const int base = tile * 32;
  if (base >= gc) return;

  const int tid = threadIdx.x;
  const int lane = tid & 63;
  const int w = tid >> 6;
  const int l15 = lane & 15;
  const int lq = lane >> 4;

  if (tid < 32) {
    int r = base + tid;
    gidx[tid] = (r < gc) ? glist[b * G_GRAPHS + r] : glist[b * G_GRAPHS];
  }
  __syncthreads();

  // stage xg rows as bf16, swizzled
#pragma unroll
  for (int it = 0; it < 16; ++it) {
    int u = it * 256 + tid;
    int r = u >> 7, c4 = u & 127;
    float4 v = *reinterpret_cast<const float4*>(&xg[(size_t)gidx[r] * D_DIM + c4 * 4]);
    ushort4_t h4;
    h4[0] = rne_bf16(v.x); h4[1] = rne_bf16(v.y);
    h4[2] = rne_bf16(v.z); h4[3] = rne_bf16(v.w);
    int byteoff = r * 1024 + ((c4 * 8) ^ ((r & 7) << 4));
    *reinterpret_cast<ushort4_t*>((char*)Ah + byteoff) = h4;
  }
  __syncthreads();

  // L1: each wave covers 12 col-tiles (192 cols)
  f32x4 acc[2][12];
#pragma unroll
  for (int i = 0; i < 2; ++i)
#pragma unroll
    for (int j = 0; j < 12; ++j) acc[i][j] = (f32x4){0.f, 0.f, 0.f, 0.f};

  const ushort_t* __restrict__ g1h =
      WG1h + (((size_t)b * 48 + w * 12) * 16) * 512 + (size_t)lane * 8;

  for (int ks = 0; ks < 16; ++ks) {
    short8 ah[2];
#pragma unroll
    for (int rt = 0; rt < 2; ++rt) {
      int R = rt * 16 + l15;
      int byteoff = R * 1024 + ((ks * 64 + lq * 16) ^ ((R & 7) << 4));
      ah[rt] = *reinterpret_cast<const short8*>((const char*)Ah + byteoff);
    }
#pragma unroll
    for (int ct = 0; ct < 12; ++ct) {
      short8 bh = *reinterpret_cast<const short8*>(g1h + (size_t)(ct * 16 + ks) * 512);
#pragma unroll
      for (int rt = 0; rt < 2; ++rt) {
        acc[rt][ct] = __builtin_amdgcn_mfma_f32_16x16x32_bf16(ah[rt], bh, acc[rt][ct], 0, 0, 0);
      }
    }
  }

  __syncthreads();  // reuse gbuf as hg (32 x 768 bf16, row stride 1536B)
  ushort_t* hgs = (ushort_t*)gbuf;
#pragma unroll
  for (int ct = 0; ct < 12; ++ct) {
    int n = w * 192 + ct * 16 + l15;
    float bias = bg_shared[b * H_DIM + n];
#pragma unroll
    for (int rt = 0; rt < 2; ++rt) {
#pragma unroll
      for (int j = 0; j < 4; ++j) {
        int row = rt * 16 + lq * 4 + j;
        float v = fmaxf(acc[rt][ct][j] + bias, 0.0f);
        int byteoff = row * 1536 + ((n * 2) ^ ((row & 7) << 4));
        *reinterpret_cast<ushort_t*>((char*)hgs + byteoff) = rne_bf16(v);
      }
    }
  }
  __syncthreads();

  // L2: 32x128, K=768. wave w covers o-tiles w*2, w*2+1
  f32x4 acc2[2][2];
#pragma unroll
  for (int i = 0; i < 2; ++i)
#pragma unroll
    for (int j = 0; j < 2; ++j) acc2[i][j] = (f32x4){0.f, 0.f, 0.f, 0.f};

  const ushort_t* __restrict__ g2 = WG2 + ((size_t)(b * 8 + w * 2) * 24 * 64 + lane) * 8;

  for (int ks = 0; ks < 24; ++ks) {
    short8 a2[2];
#pragma unroll
    for (int rt = 0; rt < 2; ++rt) {
      int R = rt * 16 + l15;
      int byteoff = R * 1536 + ((ks * 64 + lq * 16) ^ ((R & 7) << 4));
      a2[rt] = *reinterpret_cast<const short8*>((const char*)hgs + byteoff);
    }
#pragma unroll
    for (int ct = 0; ct < 2; ++ct) {
      short8 b2 = *reinterpret_cast<const short8*>(g2 + (size_t)ct * 12288 + (size_t)ks * 512);
#pragma unroll
      for (int rt = 0; rt < 2; ++rt) {
        acc2[rt][ct] = __builtin_amdgcn_mfma_f32_16x16x32_bf16(a2[rt], b2, acc2[rt][ct], 0, 0, 0);
      }
    }
  }

#pragma unroll
  for (int ct = 0; ct < 2; ++ct) {
    int o = (w * 2 + ct) * 16 + l15;
    float bo = bg_head[b * 2 * GHD + o];
#pragma unroll
    for (int rt = 0; rt < 2; ++rt) {
#pragma unroll
      for (int j = 0; j < 4; ++j) {
        int r = rt * 16 + lq * 4 + j;
        if (base + r < gc) {
          int g = gidx[r];
          float v = acc2[rt][ct][j] + bo;
          if (o < GHD) out[g * GHD + o] = v;
          else out[GV_OFF + g * GHD + (o - GHD)] = v * v;
        }
      }
    }
  }
}

// ---------------------------------------------------------------------------
extern "C" void kernel_launch(void* const* d_in, const int* in_sizes, int n_in,
                              void* d_out, int out_size, void* d_ws, size_t ws_size,
                              hipStream_t stream) {
  const float* x         = (const float*)d_in[0];
  const int*   batch     = (const int*)d_in[1];
  const int*   dsname    = (const int*)d_in[2];
  const float* Wg_shared = (const float*)d_in[3];
  const float* bg_shared = (const float*)d_in[4];
  const float* Wg_head   = (const float*)d_in[5];
  const float* bg_head   = (const float*)d_in[6];
  const float* Wn1       = (const float*)d_in[7];
  const float* bn1       = (const float*)d_in[8];
  const float* Wn2       = (const float*)d_in[9];
  const float* bn2       = (const float*)d_in[10];
  float* out = (float*)d_out;

  int* ws_i   = (int*)d_ws;
  int* cnt    = ws_i;               // 4
  int* gcnt   = ws_i + 8;           // 4
  int* gstart = ws_i + 16;          // 1025
  int* goff   = ws_i + 1056;        // 1024
  int* glist  = ws_i + 2080;        // 4096
  int* lists  = ws_i + 6176;        // 4*32768 -> end 137248
  float* xg   = (float*)(ws_i + 137248);     // 1024*512 f32
  ushort_t* WPh  = (ushort_t*)(xg + 524288); // 4*512*512 bf16
  ushort_t* W2T  = WPh + 1048576;            // 4*16*512
  ushort_t* WG1h = W2T + 32768;              // 4*48*16*64*8 = 1572864
  ushort_t* WG2  = WG1h + 1572864;           // 4*8*24*64*8 = 393216

  seg_kernel<<<5, 256, 0, stream>>>(batch, gstart);
  scan_kernel<<<1, 256, 0, stream>>>(dsname, gstart, goff, glist, cnt, gcnt);
  scatter_kernel<<<N_NODES / 256, 256, 0, stream>>>(batch, dsname, gstart, goff, lists);
  conv_w_kernel<<<256, 256, 0, stream>>>(Wn1, WPh);
  conv_w2_kernel<<<4, 256, 0, stream>>>(Wn2, W2T);
  conv_wg1_kernel<<<384, 256, 0, stream>>>(Wg_shared, WG1h);
  conv_wg2_kernel<<<4, 256, 0, stream>>>(Wg_head, WG2);
  pool_kernel<<<G_GRAPHS, 128, 0, stream>>>(x, gstart, xg);
  node_mfma_kernel<<<B_BR * (N_NODES / NBM), 256, 0, stream>>>(
      x, WPh, bn1, W2T, bn2, cnt, lists, out);
  graph_fused_kernel<<<B_BR * 32, 256, 0, stream>>>(
      xg, WG1h, bg_shared, WG2, bg_head, gcnt, glist, out);
}

// Round 7
// 219.434 us; speedup vs baseline: 3.9836x; 1.0232x over previous
//
#include <hip/hip_runtime.h>

#define N_NODES 32768
#define G_GRAPHS 1024
#define D_DIM 512
#define H_DIM 768
#define B_BR 4
#define GHD 64
#define NHD 3

// output layout (f32, concatenated flat)
#define NH_OFF (G_GRAPHS * GHD)
#define GV_OFF (G_GRAPHS * GHD + N_NODES * NHD)
#define NV_OFF (2 * G_GRAPHS * GHD + N_NODES * NHD)

typedef unsigned short ushort_t;
typedef __attribute__((ext_vector_type(8))) short short8;
typedef __attribute__((ext_vector_type(4))) float f32x4;
typedef __attribute__((ext_vector_type(4))) ushort_t ushort4_t;

__device__ __forceinline__ ushort_t rne_bf16(float v) {
  unsigned bits = __float_as_uint(v);
  return (ushort_t)((bits + 0x7fffu + ((bits >> 16) & 1u)) >> 16);
}

// ---------------------------------------------------------------------------
// per-graph segment bounds (batch is sorted)
// ---------------------------------------------------------------------------
__global__ __launch_bounds__(256) void seg_kernel(
    const int* __restrict__ batch, int* __restrict__ gstart) {
  int g = blockIdx.x * 256 + threadIdx.x;
  if (g > G_GRAPHS) return;
  if (g == G_GRAPHS) { gstart[G_GRAPHS] = N_NODES; return; }
  int lo = 0, hi = N_NODES;
  while (lo < hi) { int mid = (lo + hi) >> 1; if (batch[mid] < g) lo = mid + 1; else hi = mid; }
  gstart[g] = lo;
}

// ---------------------------------------------------------------------------
// 4-wave scan: wave b handles branch b. No atomics. Also emits pbase[] —
// 64-aligned per-branch row offsets into the packed-x buffer.
// ---------------------------------------------------------------------------
__global__ __launch_bounds__(256) void scan_kernel(
    const int* __restrict__ dsname, const int* __restrict__ gstart,
    int* __restrict__ goff, int* __restrict__ glist,
    int* __restrict__ cnt, int* __restrict__ gcnt, int* __restrict__ pbase) {
  __shared__ int scnt[4], sgcnt[4];
  const int lane = threadIdx.x & 63;
  const int b = threadIdx.x >> 6;
  int run_n = 0, run_g = 0;
  for (int c = 0; c < G_GRAPHS / 64; ++c) {
    int g = c * 64 + lane;
    int mine = (dsname[g] == b) ? 1 : 0;
    int len = mine ? (gstart[g + 1] - gstart[g]) : 0;
    int sl = len, so = mine;
#pragma unroll
    for (int off = 1; off < 64; off <<= 1) {
      int tl = __shfl_up(sl, off);
      int to = __shfl_up(so, off);
      if (lane >= off) { sl += tl; so += to; }
    }
    if (mine) {
      goff[g] = run_n + sl - len;
      glist[b * G_GRAPHS + run_g + so - 1] = g;
    }
    run_n += __shfl(sl, 63);
    run_g += __shfl(so, 63);
  }
  if (lane == 0) { scnt[b] = run_n; sgcnt[b] = run_g; }
  __syncthreads();
  if (threadIdx.x == 0) {
    int p = 0;
    for (int b2 = 0; b2 < 4; ++b2) {
      cnt[b2] = scnt[b2];
      gcnt[b2] = sgcnt[b2];
      pbase[b2] = p;
      p += (scnt[b2] + 63) & ~63;
    }
  }
}

// ---------------------------------------------------------------------------
// scatter nodes into per-branch lists (atomic-free, ordered by node id)
// ---------------------------------------------------------------------------
__global__ __launch_bounds__(256) void scatter_kernel(
    const int* __restrict__ batch, const int* __restrict__ dsname,
    const int* __restrict__ gstart, const int* __restrict__ goff,
    int* __restrict__ lists) {
  int n = blockIdx.x * 256 + threadIdx.x;
  int g = batch[n];
  int b = dsname[g];
  lists[b * N_NODES + goff[g] + (n - gstart[g])] = n;
}

// ---------------------------------------------------------------------------
// pack x: gather rows in branch-list order, convert to bf16 (RNE), bake the
// per-row XOR-16B-chunk swizzle in, so node staging can use linear
// global_load_lds while ds_reads use the swizzled address (rule #21).
// xpacked[(pbase[b]+i)*512 + cp*8 .. +8) = x[lists[b][i]][8 cols at (cp^(i&7))*8]
// ---------------------------------------------------------------------------
__global__ __launch_bounds__(256) void pack_x_kernel(
    const float* __restrict__ x, const int* __restrict__ cnt,
    const int* __restrict__ pbase, const int* __restrict__ lists,
    ushort_t* __restrict__ xp) {
  const int b = blockIdx.x >> 9;
  const int t = blockIdx.x & 511;
  const int count = cnt[b];
  if (t * 64 >= count) return;
  const int pb = pbase[b];
  const int tid = threadIdx.x;
#pragma unroll
  for (int it = 0; it < 16; ++it) {
    int u = it * 256 + tid;          // 0..4095 = 64 rows x 64 chunks
    int r = u >> 6, cp = u & 63;
    int i = t * 64 + r;
    if (i >= count) continue;        // pad rows left untouched (masked later)
    int node = lists[b * N_NODES + i];
    int g8 = cp ^ (i & 7);           // source 8-col group
    const float* sp = x + (size_t)node * D_DIM + g8 * 8;
    float4 v0 = *reinterpret_cast<const float4*>(sp);
    float4 v1 = *reinterpret_cast<const float4*>(sp + 4);
    short8 h;
    h[0] = (short)rne_bf16(v0.x); h[1] = (short)rne_bf16(v0.y);
    h[2] = (short)rne_bf16(v0.z); h[3] = (short)rne_bf16(v0.w);
    h[4] = (short)rne_bf16(v1.x); h[5] = (short)rne_bf16(v1.y);
    h[6] = (short)rne_bf16(v1.z); h[7] = (short)rne_bf16(v1.w);
    *reinterpret_cast<short8*>(xp + ((size_t)(pb + i)) * 512 + cp * 8) = h;
  }
}

// ---------------------------------------------------------------------------
// Wn1 [b][k][n] f32 -> packed MFMA-fragment-order bf16 (RNE):
// WP[b][n16][ks][lane][8], lane = lq*16+l15 holds (col n16*16+l15, k=ks*32+lq*8+j)
// ---------------------------------------------------------------------------
__global__ __launch_bounds__(256) void conv_w_kernel(
    const float* __restrict__ Wn1, ushort_t* __restrict__ WPh) {
  __shared__ float Ws[64][65];
  int b = blockIdx.x >> 6;
  int t = blockIdx.x & 63;
  int kt = t >> 3, nt = t & 7;
  const float* W = Wn1 + (size_t)b * D_DIM * D_DIM;
  for (int i = threadIdx.x; i < 64 * 64; i += 256) {
    int k = i >> 6, n = i & 63;
    Ws[k][n] = W[(size_t)(kt * 64 + k) * D_DIM + nt * 64 + n];
  }
  __syncthreads();
  for (int i = threadIdx.x; i < 64 * 8; i += 256) {
    int n = i >> 3, kq8 = i & 7;
    short8 sh;
#pragma unroll
    for (int j = 0; j < 8; ++j) sh[j] = (short)rne_bf16(Ws[kq8 * 8 + j][n]);
    int gn = nt * 64 + n, gk0 = kt * 64 + kq8 * 8;
    int n16 = gn >> 4, l15 = gn & 15;
    int ks = gk0 >> 5, lq = (gk0 >> 3) & 3;
    size_t off = ((((size_t)b * 32 + n16) * 16 + ks) * 64 + lq * 16 + l15) * 8;
    *reinterpret_cast<short8*>(WPh + off) = sh;
  }
}

// Wg_shared [b][k(512)][n(768)] f32 -> packed bf16 RNE [b][n16(48)][ks(16)][lane][8]
__global__ __launch_bounds__(256) void conv_wg1_kernel(
    const float* __restrict__ Wg, ushort_t* __restrict__ Gh) {
  __shared__ float Ws[64][65];
  int b = blockIdx.x / 96;
  int t = blockIdx.x % 96;
  int kt = t / 12, nt = t % 12;
  const float* W = Wg + (size_t)b * D_DIM * H_DIM;
  for (int i = threadIdx.x; i < 64 * 64; i += 256) {
    int k = i >> 6, n = i & 63;
    Ws[k][n] = W[(size_t)(kt * 64 + k) * H_DIM + nt * 64 + n];
  }
  __syncthreads();
  for (int i = threadIdx.x; i < 64 * 8; i += 256) {
    int n = i >> 3, kq8 = i & 7;
    short8 sh;
#pragma unroll
    for (int j = 0; j < 8; ++j) sh[j] = (short)rne_bf16(Ws[kq8 * 8 + j][n]);
    int gn = nt * 64 + n, gk0 = kt * 64 + kq8 * 8;
    int n16 = gn >> 4, l15 = gn & 15;
    int ks = gk0 >> 5, lq = (gk0 >> 3) & 3;
    size_t off = ((((size_t)b * 48 + n16) * 16 + ks) * 64 + lq * 16 + l15) * 8;
    *reinterpret_cast<short8*>(Gh + off) = sh;
  }
}

// Wg_head [b][k(768)][o(128)] f32 -> packed bf16 RNE [b][n16(8)][ks(24)][lane][8]
__global__ __launch_bounds__(256) void conv_wg2_kernel(
    const float* __restrict__ Wh, ushort_t* __restrict__ G2) {
  int b = blockIdx.x;
  const float* W = Wh + (size_t)b * H_DIM * 2 * GHD;
  for (int i = threadIdx.x; i < 8 * 24 * 64; i += 256) {
    int n16 = i / (24 * 64);
    int rem = i % (24 * 64);
    int ks = rem / 64, lane = rem % 64;
    int l15 = lane & 15, lq = lane >> 4;
    int o = n16 * 16 + l15;
    short8 sv;
#pragma unroll
    for (int j = 0; j < 8; ++j) {
      int k = ks * 32 + lq * 8 + j;
      sv[j] = (short)rne_bf16(W[(size_t)k * 128 + o]);
    }
    *reinterpret_cast<short8*>(G2 + (size_t)i * 8 + (size_t)b * (8 * 24 * 64 * 8)) = sv;
  }
}

// Wn2 [b][c][o] (o<6) -> W2T [b][o][c], o padded to 16 with zeros, bf16 RNE
__global__ __launch_bounds__(256) void conv_w2_kernel(
    const float* __restrict__ Wn2, ushort_t* __restrict__ W2T) {
  int b = blockIdx.x;
  for (int i = threadIdx.x; i < 16 * D_DIM; i += 256) {
    int o = i & 15, c = i >> 4;
    float v = (o < 6) ? Wn2[(size_t)b * D_DIM * 6 + c * 6 + o] : 0.0f;
    W2T[(size_t)b * 16 * D_DIM + o * D_DIM + c] = rne_bf16(v);
  }
}

// ---------------------------------------------------------------------------
// mean-pool per graph -> xg[1024][512] f32
// ---------------------------------------------------------------------------
__global__ __launch_bounds__(128) void pool_kernel(
    const float* __restrict__ x, const int* __restrict__ gstart,
    float* __restrict__ xg) {
  const int g = blockIdx.x;
  const int tid = threadIdx.x;
  const int start = gstart[g], end = gstart[g + 1];
  const float inv = (end > start) ? 1.0f / (float)(end - start) : 0.0f;
  float4 acc = make_float4(0.f, 0.f, 0.f, 0.f);
  for (int i = start; i < end; ++i) {
    float4 v = *reinterpret_cast<const float4*>(&x[(size_t)i * D_DIM + tid * 4]);
    acc.x += v.x; acc.y += v.y; acc.z += v.z; acc.w += v.w;
  }
  acc.x *= inv; acc.y *= inv; acc.z *= inv; acc.w *= inv;
  *reinterpret_cast<float4*>(&xg[(size_t)g * D_DIM + tid * 4]) = acc;
}

// ---------------------------------------------------------------------------
// node path: MFMA grouped GEMM, BM=64 packed rows x 512 cols per block.
// A staged via global_load_lds DMA from pre-swizzled xpacked (linear dest).
// B single bf16 packed, streamed from L2 (XCD-swizzled grid keeps per-branch
// W resident in its XCD pair's L2). Layer2 (512->6) fused via one MFMA/wave.
// ---------------------------------------------------------------------------
#define NBM 64

__global__ __launch_bounds__(256) void node_mfma_kernel(
    const ushort_t* __restrict__ xpacked,
    const ushort_t* __restrict__ WPh,
    const float* __restrict__ bn1,
    const ushort_t* __restrict__ W2T, const float* __restrict__ bn2,
    const int* __restrict__ cnt, const int* __restrict__ pbase,
    const int* __restrict__ lists,
    float* __restrict__ out) {
  __shared__ __align__(16) ushort_t Ah[NBM * 512];  // 64 KB
  __shared__ int nidx[NBM];

  // XCD swizzle: branch b -> XCDs {2b, 2b+1} (round-robin heuristic)
  const int bid = blockIdx.x;
  const int b = (bid & 7) >> 1;
  const int tile = ((bid >> 3) << 1) | (bid & 1);
  const int count = cnt[b];
  const int base = tile * NBM;
  if (base >= count) return;
  const int pb = pbase[b];

  const int tid = threadIdx.x;
  const int lane = tid & 63;
  const int w = tid >> 6;
  const int l15 = lane & 15;
  const int lq = lane >> 4;

  if (tid < NBM) {
    int r = base + tid;
    nidx[tid] = (r < count) ? lists[b * N_NODES + r] : lists[b * N_NODES];
  }

  // stage A: 16 rows per wave, 1 KB each, direct DMA (linear, pre-swizzled src)
  const char* srow = (const char*)(xpacked + (size_t)(pb + base) * 512);
#pragma unroll
  for (int i = 0; i < 16; ++i) {
    int row = w * 16 + i;
    const void* gsrc = srow + (size_t)row * 1024 + (size_t)lane * 16;
    __builtin_amdgcn_global_load_lds(
        (const __attribute__((address_space(1))) void*)gsrc,
        (__attribute__((address_space(3))) void*)((char*)Ah + row * 1024),
        16, 0, 0);
  }
  __syncthreads();

  f32x4 acc[4][8];
#pragma unroll
  for (int i = 0; i < 4; ++i)
#pragma unroll
    for (int j = 0; j < 8; ++j) acc[i][j] = (f32x4){0.f, 0.f, 0.f, 0.f};

  const ushort_t* __restrict__ wph =
      WPh + (((size_t)b * 32 + w * 8) * 16) * 512 + (size_t)lane * 8;

  for (int ks = 0; ks < 16; ++ks) {
    short8 ah[4];
#pragma unroll
    for (int rt = 0; rt < 4; ++rt) {
      int R = rt * 16 + l15;
      int byteoff = R * 1024 + ((ks * 64 + lq * 16) ^ ((R & 7) << 4));
      ah[rt] = *reinterpret_cast<const short8*>((const char*)Ah + byteoff);
    }
#pragma unroll
    for (int ct = 0; ct < 8; ++ct) {
      short8 bh = *reinterpret_cast<const short8*>(wph + (size_t)(ct * 16 + ks) * 512);
#pragma unroll
      for (int rt = 0; rt < 4; ++rt) {
        acc[rt][ct] = __builtin_amdgcn_mfma_f32_16x16x32_bf16(ah[rt], bh, acc[rt][ct], 0, 0, 0);
      }
    }
  }

  __syncthreads();  // done reading A; reuse Ah as bf16 hn tile (64 x 512)
  ushort_t* hn = Ah;
#pragma unroll
  for (int ct = 0; ct < 8; ++ct) {
    int n = w * 128 + ct * 16 + l15;
    float bias = bn1[b * D_DIM + n];
#pragma unroll
    for (int rt = 0; rt < 4; ++rt) {
#pragma unroll
      for (int j = 0; j < 4; ++j) {
        int row = rt * 16 + lq * 4 + j;
        float v = fmaxf(acc[rt][ct][j] + bias, 0.0f);
        int byteoff = row * 1024 + ((n * 2) ^ ((row & 7) << 4));
        *reinterpret_cast<ushort_t*>((char*)hn + byteoff) = rne_bf16(v);
      }
    }
  }
  __syncthreads();

  // second layer: wave w handles row-tile w (rows w*16 .. w*16+15)
  {
    f32x4 acc2 = (f32x4){0.f, 0.f, 0.f, 0.f};
    const ushort_t* __restrict__ w2 = W2T + (size_t)b * (16 * 512) + (size_t)l15 * 512 + lq * 8;
    const int R = w * 16 + l15;
#pragma unroll
    for (int ks = 0; ks < 16; ++ks) {
      int byteoff = R * 1024 + ((ks * 64 + lq * 16) ^ ((R & 7) << 4));
      short8 a2 = *reinterpret_cast<const short8*>((const char*)hn + byteoff);
      short8 b2 = *reinterpret_cast<const short8*>(w2 + ks * 32);
      acc2 = __builtin_amdgcn_mfma_f32_16x16x32_bf16(a2, b2, acc2, 0, 0, 0);
    }
    int o = l15;
    if (o < 6) {
      float bo = bn2[b * 6 + o];
#pragma unroll
      for (int j = 0; j < 4; ++j) {
        int r = w * 16 + lq * 4 + j;
        if (base + r < count) {
          int n = nidx[r];
          float v = acc2[j] + bo;
          if (o < NHD) out[NH_OFF + n * NHD + o] = v;
          else out[NV_OFF + n * NHD + (o - NHD)] = v * v;
        }
      }
    }
  }
}

// ---------------------------------------------------------------------------
// fused graph path: per block = 32 branch-grouped graphs, full bf16.
// ---------------------------------------------------------------------------
__global__ __launch_bounds__(256) void graph_fused_kernel(
    const float* __restrict__ xg,
    const ushort_t* __restrict__ WG1h,
    const float* __restrict__ bg_shared,
    const ushort_t* __restrict__ WG2, const float* __restrict__ bg_head,
    const int* __restrict__ gcnt, const int* __restrict__ glist,
    float* __restrict__ out) {
  __shared__ __align__(16) char gbuf[49152];
  __shared__ int gidx[32];
  ushort_t* Ah = (ushort_t*)gbuf;

  const int b = blockIdx.x >> 5;
  const int tile = blockIdx.x & 31;
  const int gc = gcnt[b];
  const int base = tile * 32;
  if (base >= gc) return;

  const int tid = threadIdx.x;
  const int lane = tid & 63;
  const int w = tid >> 6;
  const int l15 = lane & 15;
  const int lq = lane >> 4;

  if (tid < 32) {
    int r = base + tid;
    gidx[tid] = (r < gc) ? glist[b * G_GRAPHS + r] : glist[b * G_GRAPHS];
  }
  __syncthreads();

#pragma unroll
  for (int it = 0; it < 16; ++it) {
    int u = it * 256 + tid;
    int r = u >> 7, c4 = u & 127;
    float4 v = *reinterpret_cast<const float4*>(&xg[(size_t)gidx[r] * D_DIM + c4 * 4]);
    ushort4_t h4;
    h4[0] = rne_bf16(v.x); h4[1] = rne_bf16(v.y);
    h4[2] = rne_bf16(v.z); h4[3] = rne_bf16(v.w);
    int byteoff = r * 1024 + ((c4 * 8) ^ ((r & 7) << 4));
    *reinterpret_cast<ushort4_t*>((char*)Ah + byteoff) = h4;
  }
  __syncthreads();

  f32x4 acc[2][12];
#pragma unroll
  for (int i = 0; i < 2; ++i)
#pragma unroll
    for (int j = 0; j < 12; ++j) acc[i][j] = (f32x4){0.f, 0.f, 0.f, 0.f};

  const ushort_t* __restrict__ g1h =
      WG1h + (((size_t)b * 48 + w * 12) * 16) * 512 + (size_t)lane * 8;

  for (int ks = 0; ks < 16; ++ks) {
    short8 ah[2];
#pragma unroll
    for (int rt = 0; rt < 2; ++rt) {
      int R = rt * 16 + l15;
      int byteoff = R * 1024 + ((ks * 64 + lq * 16) ^ ((R & 7) << 4));
      ah[rt] = *reinterpret_cast<const short8*>((const char*)Ah + byteoff);
    }
#pragma unroll
    for (int ct = 0; ct < 12; ++ct) {
      short8 bh = *reinterpret_cast<const short8*>(g1h + (size_t)(ct * 16 + ks) * 512);
#pragma unroll
      for (int rt = 0; rt < 2; ++rt) {
        acc[rt][ct] = __builtin_amdgcn_mfma_f32_16x16x32_bf16(ah[rt], bh, acc[rt][ct], 0, 0, 0);
      }
    }
  }

  __syncthreads();
  ushort_t* hgs = (ushort_t*)gbuf;
#pragma unroll
  for (int ct = 0; ct < 12; ++ct) {
    int n = w * 192 + ct * 16 + l15;
    float bias = bg_shared[b * H_DIM + n];
#pragma unroll
    for (int rt = 0; rt < 2; ++rt) {
#pragma unroll
      for (int j = 0; j < 4; ++j) {
        int row = rt * 16 + lq * 4 + j;
        float v = fmaxf(acc[rt][ct][j] + bias, 0.0f);
        int byteoff = row * 1536 + ((n * 2) ^ ((row & 7) << 4));
        *reinterpret_cast<ushort_t*>((char*)hgs + byteoff) = rne_bf16(v);
      }
    }
  }
  __syncthreads();

  f32x4 acc2[2][2];
#pragma unroll
  for (int i = 0; i < 2; ++i)
#pragma unroll
    for (int j = 0; j < 2; ++j) acc2[i][j] = (f32x4){0.f, 0.f, 0.f, 0.f};

  const ushort_t* __restrict__ g2 = WG2 + ((size_t)(b * 8 + w * 2) * 24 * 64 + lane) * 8;

  for (int ks = 0; ks < 24; ++ks) {
    short8 a2[2];
#pragma unroll
    for (int rt = 0; rt < 2; ++rt) {
      int R = rt * 16 + l15;
      int byteoff = R * 1536 + ((ks * 64 + lq * 16) ^ ((R & 7) << 4));
      a2[rt] = *reinterpret_cast<const short8*>((const char*)hgs + byteoff);
    }
#pragma unroll
    for (int ct = 0; ct < 2; ++ct) {
      short8 b2 = *reinterpret_cast<const short8*>(g2 + (size_t)ct * 12288 + (size_t)ks * 512);
#pragma unroll
      for (int rt = 0; rt < 2; ++rt) {
        acc2[rt][ct] = __builtin_amdgcn_mfma_f32_16x16x32_bf16(a2[rt], b2, acc2[rt][ct], 0, 0, 0);
      }
    }
  }

#pragma unroll
  for (int ct = 0; ct < 2; ++ct) {
    int o = (w * 2 + ct) * 16 + l15;
    float bo = bg_head[b * 2 * GHD + o];
#pragma unroll
    for (int rt = 0; rt < 2; ++rt) {
#pragma unroll
      for (int j = 0; j < 4; ++j) {
        int r = rt * 16 + lq * 4 + j;
        if (base + r < gc) {
          int g = gidx[r];
          float v = acc2[rt][ct][j] + bo;
          if (o < GHD) out[g * GHD + o] = v;
          else out[GV_OFF + g * GHD + (o - GHD)] = v * v;
        }
      }
    }
  }
}

// ---------------------------------------------------------------------------
extern "C" void kernel_launch(void* const* d_in, const int* in_sizes, int n_in,
                              void* d_out, int out_size, void* d_ws, size_t ws_size,
                              hipStream_t stream) {
  const float* x         = (const float*)d_in[0];
  const int*   batch     = (const int*)d_in[1];
  const int*   dsname    = (const int*)d_in[2];
  const float* Wg_shared = (const float*)d_in[3];
  const float* bg_shared = (const float*)d_in[4];
  const float* Wg_head   = (const float*)d_in[5];
  const float* bg_head   = (const float*)d_in[6];
  const float* Wn1       = (const float*)d_in[7];
  const float* bn1       = (const float*)d_in[8];
  const float* Wn2       = (const float*)d_in[9];
  const float* bn2       = (const float*)d_in[10];
  float* out = (float*)d_out;

  int* ws_i   = (int*)d_ws;
  int* cnt    = ws_i;               // 4
  int* gcnt   = ws_i + 8;           // 4
  int* pbase  = ws_i + 12;          // 4
  int* gstart = ws_i + 16;          // 1025
  int* goff   = ws_i + 1056;        // 1024
  int* glist  = ws_i + 2080;        // 4096
  int* lists  = ws_i + 6176;        // 4*32768 -> end 137248
  float* xg   = (float*)(ws_i + 137248);     // 1024*512 f32
  ushort_t* WPh  = (ushort_t*)(xg + 524288); // 4*512*512 bf16
  ushort_t* W2T  = WPh + 1048576;            // 4*16*512
  ushort_t* WG1h = W2T + 32768;              // 1572864
  ushort_t* WG2  = WG1h + 1572864;           // 393216
  ushort_t* xpacked = WG2 + 393216;          // 33024 rows * 512 bf16 ~= 33.8 MB

  seg_kernel<<<5, 256, 0, stream>>>(batch, gstart);
  scan_kernel<<<1, 256, 0, stream>>>(dsname, gstart, goff, glist, cnt, gcnt, pbase);
  scatter_kernel<<<N_NODES / 256, 256, 0, stream>>>(batch, dsname, gstart, goff, lists);
  pack_x_kernel<<<2048, 256, 0, stream>>>(x, cnt, pbase, lists, xpacked);
  conv_w_kernel<<<256, 256, 0, stream>>>(Wn1, WPh);
  conv_w2_kernel<<<4, 256, 0, stream>>>(Wn2, W2T);
  conv_wg1_kernel<<<384, 256, 0, stream>>>(Wg_shared, WG1h);
  conv_wg2_kernel<<<4, 256, 0, stream>>>(Wg_head, WG2);
  pool_kernel<<<G_GRAPHS, 128, 0, stream>>>(x, gstart, xg);
  node_mfma_kernel<<<B_BR * (N_NODES / NBM), 256, 0, stream>>>(
      xpacked, WPh, bn1, W2T, bn2, cnt, pbase, lists, out);
  graph_fused_kernel<<<B_BR * 32, 256, 0, stream>>>(
      xg, WG1h, bg_shared, WG2, bg_head, gcnt, glist, out);
}

// Round 8
// 193.853 us; speedup vs baseline: 4.5093x; 1.1320x over previous
//
#include <hip/hip_runtime.h>

#define N_NODES 32768
#define G_GRAPHS 1024
#define D_DIM 512
#define H_DIM 768
#define B_BR 4
#define GHD 64
#define NHD 3

// output layout (f32, concatenated flat)
#define NH_OFF (G_GRAPHS * GHD)
#define GV_OFF (G_GRAPHS * GHD + N_NODES * NHD)
#define NV_OFF (2 * G_GRAPHS * GHD + N_NODES * NHD)

typedef unsigned short ushort_t;
typedef __attribute__((ext_vector_type(8))) short short8;
typedef __attribute__((ext_vector_type(4))) float f32x4;
typedef __attribute__((ext_vector_type(4))) ushort_t ushort4_t;

__device__ __forceinline__ ushort_t rne_bf16(float v) {
  unsigned bits = __float_as_uint(v);
  return (ushort_t)((bits + 0x7fffu + ((bits >> 16) & 1u)) >> 16);
}

// ---------------------------------------------------------------------------
// fused segment-bounds + 4-wave branch scan. One block, 1024 threads.
// ---------------------------------------------------------------------------
__global__ __launch_bounds__(1024) void segscan_kernel(
    const int* __restrict__ batch, const int* __restrict__ dsname,
    int* __restrict__ gstart, int* __restrict__ goff, int* __restrict__ glist,
    int* __restrict__ cnt, int* __restrict__ gcnt, int* __restrict__ pbase) {
  __shared__ int sg[G_GRAPHS + 1];
  __shared__ int scnt[4], sgcnt[4];
  const int tid = threadIdx.x;
  {
    int g = tid;
    int lo = 0, hi = N_NODES;
    while (lo < hi) { int mid = (lo + hi) >> 1; if (batch[mid] < g) lo = mid + 1; else hi = mid; }
    sg[g] = lo; gstart[g] = lo;
    if (tid == 0) { sg[G_GRAPHS] = N_NODES; gstart[G_GRAPHS] = N_NODES; }
  }
  __syncthreads();
  if (tid < 256) {
    const int lane = tid & 63;
    const int b = tid >> 6;
    int run_n = 0, run_g = 0;
    for (int c = 0; c < G_GRAPHS / 64; ++c) {
      int g = c * 64 + lane;
      int mine = (dsname[g] == b) ? 1 : 0;
      int len = mine ? (sg[g + 1] - sg[g]) : 0;
      int sl = len, so = mine;
#pragma unroll
      for (int off = 1; off < 64; off <<= 1) {
        int tl = __shfl_up(sl, off);
        int to = __shfl_up(so, off);
        if (lane >= off) { sl += tl; so += to; }
      }
      if (mine) {
        goff[g] = run_n + sl - len;
        glist[b * G_GRAPHS + run_g + so - 1] = g;
      }
      run_n += __shfl(sl, 63);
      run_g += __shfl(so, 63);
    }
    if (lane == 0) { scnt[b] = run_n; sgcnt[b] = run_g; }
  }
  __syncthreads();
  if (tid == 0) {
    int p = 0;
    for (int b2 = 0; b2 < 4; ++b2) {
      cnt[b2] = scnt[b2];
      gcnt[b2] = sgcnt[b2];
      pbase[b2] = p;
      p += (scnt[b2] + 63) & ~63;
    }
  }
}

// ---------------------------------------------------------------------------
// mean-pool per graph -> xgb[1024][512] bf16 (RNE)
// ---------------------------------------------------------------------------
__global__ __launch_bounds__(128) void pool_kernel(
    const float* __restrict__ x, const int* __restrict__ gstart,
    ushort_t* __restrict__ xgb) {
  const int g = blockIdx.x;
  const int tid = threadIdx.x;
  const int start = gstart[g], end = gstart[g + 1];
  const float inv = (end > start) ? 1.0f / (float)(end - start) : 0.0f;
  float4 acc = make_float4(0.f, 0.f, 0.f, 0.f);
  for (int i = start; i < end; ++i) {
    float4 v = *reinterpret_cast<const float4*>(&x[(size_t)i * D_DIM + tid * 4]);
    acc.x += v.x; acc.y += v.y; acc.z += v.z; acc.w += v.w;
  }
  ushort4_t h4;
  h4[0] = rne_bf16(acc.x * inv); h4[1] = rne_bf16(acc.y * inv);
  h4[2] = rne_bf16(acc.z * inv); h4[3] = rne_bf16(acc.w * inv);
  *reinterpret_cast<ushort4_t*>(&xgb[(size_t)g * D_DIM + tid * 4]) = h4;
}

// ---------------------------------------------------------------------------
// pack x (fused scatter): iterate nodes LINEARLY (coalesced x reads),
// compute packed dest row arithmetically, bake per-row XOR swizzle in,
// emit lists[] as a side effect. 512 blocks x 64 nodes.
// ---------------------------------------------------------------------------
__global__ __launch_bounds__(256) void pack_x_kernel(
    const float* __restrict__ x, const int* __restrict__ batch,
    const int* __restrict__ dsname, const int* __restrict__ gstart,
    const int* __restrict__ goff, const int* __restrict__ pbase,
    int* __restrict__ lists, ushort_t* __restrict__ xp) {
  const int blk = blockIdx.x;
  const int tid = threadIdx.x;
#pragma unroll
  for (int it = 0; it < 16; ++it) {
    int u = it * 256 + tid;          // 64 nodes x 64 chunks
    int r = u >> 6, cp = u & 63;
    int n = blk * 64 + r;
    int g = batch[n];
    int b = dsname[g];
    int i = goff[g] + (n - gstart[g]);
    if (cp == 0) lists[b * N_NODES + i] = n;
    int dest = pbase[b] + i;
    int g8 = cp ^ (i & 7);
    const float* sp = x + (size_t)n * D_DIM + g8 * 8;
    float4 v0 = *reinterpret_cast<const float4*>(sp);
    float4 v1 = *reinterpret_cast<const float4*>(sp + 4);
    short8 h;
    h[0] = (short)rne_bf16(v0.x); h[1] = (short)rne_bf16(v0.y);
    h[2] = (short)rne_bf16(v0.z); h[3] = (short)rne_bf16(v0.w);
    h[4] = (short)rne_bf16(v1.x); h[5] = (short)rne_bf16(v1.y);
    h[6] = (short)rne_bf16(v1.z); h[7] = (short)rne_bf16(v1.w);
    *reinterpret_cast<short8*>(xp + (size_t)dest * 512 + cp * 8) = h;
  }
}

// ---------------------------------------------------------------------------
// combined weight conversion kernel (all four weight tensors), dispatch by bid
// ---------------------------------------------------------------------------
__global__ __launch_bounds__(256) void conv_all_kernel(
    const float* __restrict__ Wn1, ushort_t* __restrict__ WPh,
    const float* __restrict__ Wg1, ushort_t* __restrict__ WG1,
    const float* __restrict__ Wgh, ushort_t* __restrict__ WG2,
    const float* __restrict__ Wn2, ushort_t* __restrict__ W2T) {
  __shared__ float Ws[64][65];
  const int bid = blockIdx.x;
  if (bid < 256) {  // Wn1 [b][k(512)][n(512)] -> WPh [b][n16(32)][ks(16)][lane][8]
    int b = bid >> 6, t = bid & 63;
    int kt = t >> 3, nt = t & 7;
    const float* W = Wn1 + (size_t)b * D_DIM * D_DIM;
    for (int i = threadIdx.x; i < 64 * 64; i += 256) {
      int k = i >> 6, n = i & 63;
      Ws[k][n] = W[(size_t)(kt * 64 + k) * D_DIM + nt * 64 + n];
    }
    __syncthreads();
    for (int i = threadIdx.x; i < 64 * 8; i += 256) {
      int n = i >> 3, kq8 = i & 7;
      short8 sh;
#pragma unroll
      for (int j = 0; j < 8; ++j) sh[j] = (short)rne_bf16(Ws[kq8 * 8 + j][n]);
      int gn = nt * 64 + n, gk0 = kt * 64 + kq8 * 8;
      int n16 = gn >> 4, l15 = gn & 15;
      int ks = gk0 >> 5, lq = (gk0 >> 3) & 3;
      size_t off = ((((size_t)b * 32 + n16) * 16 + ks) * 64 + lq * 16 + l15) * 8;
      *reinterpret_cast<short8*>(WPh + off) = sh;
    }
  } else if (bid < 640) {  // Wg_shared [b][k(512)][n(768)] -> WG1 [b][n16(48)][ks(16)][lane][8]
    int l2 = bid - 256;
    int b = l2 / 96, t = l2 % 96;
    int kt = t / 12, nt = t % 12;
    const float* W = Wg1 + (size_t)b * D_DIM * H_DIM;
    for (int i = threadIdx.x; i < 64 * 64; i += 256) {
      int k = i >> 6, n = i & 63;
      Ws[k][n] = W[(size_t)(kt * 64 + k) * H_DIM + nt * 64 + n];
    }
    __syncthreads();
    for (int i = threadIdx.x; i < 64 * 8; i += 256) {
      int n = i >> 3, kq8 = i & 7;
      short8 sh;
#pragma unroll
      for (int j = 0; j < 8; ++j) sh[j] = (short)rne_bf16(Ws[kq8 * 8 + j][n]);
      int gn = nt * 64 + n, gk0 = kt * 64 + kq8 * 8;
      int n16 = gn >> 4, l15 = gn & 15;
      int ks = gk0 >> 5, lq = (gk0 >> 3) & 3;
      size_t off = ((((size_t)b * 48 + n16) * 16 + ks) * 64 + lq * 16 + l15) * 8;
      *reinterpret_cast<short8*>(WG1 + off) = sh;
    }
  } else if (bid < 644) {  // Wg_head [b][k(768)][o(128)] -> WG2 [b][n16(8)][ks(24)][lane][8]
    int b = bid - 640;
    const float* W = Wgh + (size_t)b * H_DIM * 2 * GHD;
    for (int i = threadIdx.x; i < 8 * 24 * 64; i += 256) {
      int n16 = i / (24 * 64);
      int rem = i % (24 * 64);
      int ks = rem / 64, lane = rem % 64;
      int l15 = lane & 15, lq = lane >> 4;
      int o = n16 * 16 + l15;
      short8 sv;
#pragma unroll
      for (int j = 0; j < 8; ++j) {
        int k = ks * 32 + lq * 8 + j;
        sv[j] = (short)rne_bf16(W[(size_t)k * 128 + o]);
      }
      *reinterpret_cast<short8*>(WG2 + (size_t)i * 8 + (size_t)b * (8 * 24 * 64 * 8)) = sv;
    }
  } else {  // Wn2 [b][c][o<6] -> W2T [b][o(16 pad)][c]
    int b = bid - 644;
    for (int i = threadIdx.x; i < 16 * D_DIM; i += 256) {
      int o = i & 15, c = i >> 4;
      float v = (o < 6) ? Wn2[(size_t)b * D_DIM * 6 + c * 6 + o] : 0.0f;
      W2T[(size_t)b * 16 * D_DIM + o * D_DIM + c] = rne_bf16(v);
    }
  }
}

// ---------------------------------------------------------------------------
// node path: 8-wave (512-thread) MFMA GEMM, 64 packed rows x 512 cols/block.
// Wave w owns cols [w*64, w*64+64). A via global_load_lds DMA (pre-swizzled
// source). 2 blocks/CU -> 16 waves/CU for latency hiding.
// ---------------------------------------------------------------------------
#define NBM 64

__global__ __launch_bounds__(512, 4) void node_mfma_kernel(
    const ushort_t* __restrict__ xpacked,
    const ushort_t* __restrict__ WPh,
    const float* __restrict__ bn1,
    const ushort_t* __restrict__ W2T, const float* __restrict__ bn2,
    const int* __restrict__ cnt, const int* __restrict__ pbase,
    const int* __restrict__ lists,
    float* __restrict__ out) {
  __shared__ __align__(16) ushort_t Ah[NBM * 512];  // 64 KB
  __shared__ int nidx[NBM];

  const int bid = blockIdx.x;
  const int b = bid >> 9;
  const int tile = bid & 511;
  const int count = cnt[b];
  const int base = tile * NBM;
  if (base >= count) return;
  const int pb = pbase[b];

  const int tid = threadIdx.x;
  const int lane = tid & 63;
  const int w = tid >> 6;          // 0..7
  const int l15 = lane & 15;
  const int lq = lane >> 4;

  if (tid < NBM) {
    int r = base + tid;
    nidx[tid] = (r < count) ? lists[b * N_NODES + r] : lists[b * N_NODES];
  }

  // stage A: 8 rows per wave, 1 KB each (linear dest, pre-swizzled src)
  const char* srow = (const char*)(xpacked + (size_t)(pb + base) * 512);
#pragma unroll
  for (int i = 0; i < 8; ++i) {
    int row = w * 8 + i;
    const void* gsrc = srow + (size_t)row * 1024 + (size_t)lane * 16;
    __builtin_amdgcn_global_load_lds(
        (const __attribute__((address_space(1))) void*)gsrc,
        (__attribute__((address_space(3))) void*)((char*)Ah + row * 1024),
        16, 0, 0);
  }
  __syncthreads();

  f32x4 acc[4][4];
#pragma unroll
  for (int i = 0; i < 4; ++i)
#pragma unroll
    for (int j = 0; j < 4; ++j) acc[i][j] = (f32x4){0.f, 0.f, 0.f, 0.f};

  const ushort_t* __restrict__ wph =
      WPh + (((size_t)b * 32 + w * 4) * 16) * 512 + (size_t)lane * 8;

  for (int ks = 0; ks < 16; ++ks) {
    short8 ah[4];
#pragma unroll
    for (int rt = 0; rt < 4; ++rt) {
      int R = rt * 16 + l15;
      int byteoff = R * 1024 + ((ks * 64 + lq * 16) ^ ((R & 7) << 4));
      ah[rt] = *reinterpret_cast<const short8*>((const char*)Ah + byteoff);
    }
#pragma unroll
    for (int ct = 0; ct < 4; ++ct) {
      short8 bh = *reinterpret_cast<const short8*>(wph + (size_t)(ct * 16 + ks) * 512);
#pragma unroll
      for (int rt = 0; rt < 4; ++rt) {
        acc[rt][ct] = __builtin_amdgcn_mfma_f32_16x16x32_bf16(ah[rt], bh, acc[rt][ct], 0, 0, 0);
      }
    }
  }

  __syncthreads();  // done reading A; reuse Ah as bf16 hn tile (64 x 512)
  ushort_t* hn = Ah;
#pragma unroll
  for (int ct = 0; ct < 4; ++ct) {
    int n = w * 64 + ct * 16 + l15;
    float bias = bn1[b * D_DIM + n];
#pragma unroll
    for (int rt = 0; rt < 4; ++rt) {
#pragma unroll
      for (int j = 0; j < 4; ++j) {
        int row = rt * 16 + lq * 4 + j;
        float v = fmaxf(acc[rt][ct][j] + bias, 0.0f);
        int byteoff = row * 1024 + ((n * 2) ^ ((row & 7) << 4));
        *reinterpret_cast<ushort_t*>((char*)hn + byteoff) = rne_bf16(v);
      }
    }
  }
  __syncthreads();

  // second layer: waves 0..3 each handle one 16-row tile
  if (w < 4) {
    f32x4 acc2 = (f32x4){0.f, 0.f, 0.f, 0.f};
    const ushort_t* __restrict__ w2 = W2T + (size_t)b * (16 * 512) + (size_t)l15 * 512 + lq * 8;
    const int R = w * 16 + l15;
#pragma unroll
    for (int ks = 0; ks < 16; ++ks) {
      int byteoff = R * 1024 + ((ks * 64 + lq * 16) ^ ((R & 7) << 4));
      short8 a2 = *reinterpret_cast<const short8*>((const char*)hn + byteoff);
      short8 b2 = *reinterpret_cast<const short8*>(w2 + ks * 32);
      acc2 = __builtin_amdgcn_mfma_f32_16x16x32_bf16(a2, b2, acc2, 0, 0, 0);
    }
    int o = l15;
    if (o < 6) {
      float bo = bn2[b * 6 + o];
#pragma unroll
      for (int j = 0; j < 4; ++j) {
        int r = w * 16 + lq * 4 + j;
        if (base + r < count) {
          int n = nidx[r];
          float v = acc2[j] + bo;
          if (o < NHD) out[NH_OFF + n * NHD + o] = v;
          else out[NV_OFF + n * NHD + (o - NHD)] = v * v;
        }
      }
    }
  }
}

// ---------------------------------------------------------------------------
// graph L1: 1-wave blocks, 16 graphs x 192 cols. A gathered from xgb (bf16),
// B from packed WG1. relu+bias -> hgb bf16.
// grid: b(4) x rowtile(64) x colgroup(4)
// ---------------------------------------------------------------------------
__global__ __launch_bounds__(64) void gemm_g1_kernel(
    const ushort_t* __restrict__ xgb, const ushort_t* __restrict__ WG1,
    const float* __restrict__ bg_shared,
    const int* __restrict__ gcnt, const int* __restrict__ glist,
    ushort_t* __restrict__ hgb) {
  const int bid = blockIdx.x;
  const int cg = bid & 3;
  const int rt = (bid >> 2) & 63;
  const int b = bid >> 8;
  const int gc = gcnt[b];
  const int base = rt * 16;
  if (base >= gc) return;
  const int lane = threadIdx.x;
  const int l15 = lane & 15, lq = lane >> 4;

  int arow_idx = (base + l15 < gc) ? base + l15 : base;
  int ag = glist[b * G_GRAPHS + arow_idx];
  const ushort_t* __restrict__ arow = xgb + (size_t)ag * D_DIM + lq * 8;
  const ushort_t* __restrict__ g1 =
      WG1 + (((size_t)b * 48 + cg * 12) * 16) * 512 + (size_t)lane * 8;

  f32x4 acc[12];
#pragma unroll
  for (int j = 0; j < 12; ++j) acc[j] = (f32x4){0.f, 0.f, 0.f, 0.f};

  for (int ks = 0; ks < 16; ++ks) {
    short8 a = *reinterpret_cast<const short8*>(arow + ks * 32);
#pragma unroll
    for (int ct = 0; ct < 12; ++ct) {
      short8 bh = *reinterpret_cast<const short8*>(g1 + (size_t)(ct * 16 + ks) * 512);
      acc[ct] = __builtin_amdgcn_mfma_f32_16x16x32_bf16(a, bh, acc[ct], 0, 0, 0);
    }
  }

  int grow[4];
#pragma unroll
  for (int j = 0; j < 4; ++j) {
    int r = base + lq * 4 + j;
    grow[j] = (r < gc) ? glist[b * G_GRAPHS + r] : -1;
  }
#pragma unroll
  for (int ct = 0; ct < 12; ++ct) {
    int h = cg * 192 + ct * 16 + l15;
    float bias = bg_shared[b * H_DIM + h];
#pragma unroll
    for (int j = 0; j < 4; ++j) {
      if (grow[j] >= 0) {
        float v = fmaxf(acc[ct][j] + bias, 0.0f);
        hgb[(size_t)grow[j] * H_DIM + h] = rne_bf16(v);
      }
    }
  }
}

// ---------------------------------------------------------------------------
// graph L2: 1-wave blocks, 16 graphs x 64 cols. A gathered from hgb.
// grid: b(4) x rowtile(64) x colgroup(2)
// ---------------------------------------------------------------------------
__global__ __launch_bounds__(64) void gemm_g2_kernel(
    const ushort_t* __restrict__ hgb, const ushort_t* __restrict__ WG2,
    const float* __restrict__ bg_head,
    const int* __restrict__ gcnt, const int* __restrict__ glist,
    float* __restrict__ out) {
  const int bid = blockIdx.x;
  const int cg = bid & 1;
  const int rt = (bid >> 1) & 63;
  const int b = bid >> 7;
  const int gc = gcnt[b];
  const int base = rt * 16;
  if (base >= gc) return;
  const int lane = threadIdx.x;
  const int l15 = lane & 15, lq = lane >> 4;

  int arow_idx = (base + l15 < gc) ? base + l15 : base;
  int ag = glist[b * G_GRAPHS + arow_idx];
  const ushort_t* __restrict__ arow = hgb + (size_t)ag * H_DIM + lq * 8;
  const ushort_t* __restrict__ g2 =
      WG2 + (size_t)(b * 8 + cg * 4) * (24 * 512) + (size_t)lane * 8;

  f32x4 acc[4];
#pragma unroll
  for (int j = 0; j < 4; ++j) acc[j] = (f32x4){0.f, 0.f, 0.f, 0.f};

  for (int ks = 0; ks < 24; ++ks) {
    short8 a = *reinterpret_cast<const short8*>(arow + ks * 32);
#pragma unroll
    for (int ct = 0; ct < 4; ++ct) {
      short8 bh = *reinterpret_cast<const short8*>(g2 + (size_t)(ct * 24 + ks) * 512);
      acc[ct] = __builtin_amdgcn_mfma_f32_16x16x32_bf16(a, bh, acc[ct], 0, 0, 0);
    }
  }

  int grow[4];
#pragma unroll
  for (int j = 0; j < 4; ++j) {
    int r = base + lq * 4 + j;
    grow[j] = (r < gc) ? glist[b * G_GRAPHS + r] : -1;
  }
#pragma unroll
  for (int ct = 0; ct < 4; ++ct) {
    int o = cg * 64 + ct * 16 + l15;
    float bo = bg_head[b * 2 * GHD + o];
#pragma unroll
    for (int j = 0; j < 4; ++j) {
      if (grow[j] >= 0) {
        float v = acc[ct][j] + bo;
        if (o < GHD) out[grow[j] * GHD + o] = v;
        else out[GV_OFF + grow[j] * GHD + (o - GHD)] = v * v;
      }
    }
  }
}

// ---------------------------------------------------------------------------
extern "C" void kernel_launch(void* const* d_in, const int* in_sizes, int n_in,
                              void* d_out, int out_size, void* d_ws, size_t ws_size,
                              hipStream_t stream) {
  const float* x         = (const float*)d_in[0];
  const int*   batch     = (const int*)d_in[1];
  const int*   dsname    = (const int*)d_in[2];
  const float* Wg_shared = (const float*)d_in[3];
  const float* bg_shared = (const float*)d_in[4];
  const float* Wg_head   = (const float*)d_in[5];
  const float* bg_head   = (const float*)d_in[6];
  const float* Wn1       = (const float*)d_in[7];
  const float* bn1       = (const float*)d_in[8];
  const float* Wn2       = (const float*)d_in[9];
  const float* bn2       = (const float*)d_in[10];
  float* out = (float*)d_out;

  int* ws_i   = (int*)d_ws;
  int* cnt    = ws_i;               // 4
  int* gcnt   = ws_i + 8;           // 4
  int* pbase  = ws_i + 12;          // 4
  int* gstart = ws_i + 16;          // 1025
  int* goff   = ws_i + 1056;        // 1024
  int* glist  = ws_i + 2080;        // 4096
  int* lists  = ws_i + 6176;        // 4*32768 -> end 137248
  ushort_t* xgb  = (ushort_t*)(ws_i + 137248);  // 1024*512
  ushort_t* WPh  = xgb + 524288;                // 4*512*512
  ushort_t* W2T  = WPh + 1048576;               // 4*16*512
  ushort_t* WG1  = W2T + 32768;                 // 4*48*16*64*8 = 1572864
  ushort_t* WG2  = WG1 + 1572864;               // 4*8*24*64*8 = 393216
  ushort_t* hgb  = WG2 + 393216;                // 1024*768
  ushort_t* xpacked = hgb + 786432;             // 33024 rows * 512

  segscan_kernel<<<1, 1024, 0, stream>>>(batch, dsname, gstart, goff, glist,
                                         cnt, gcnt, pbase);
  pool_kernel<<<G_GRAPHS, 128, 0, stream>>>(x, gstart, xgb);
  pack_x_kernel<<<N_NODES / 64, 256, 0, stream>>>(x, batch, dsname, gstart,
                                                  goff, pbase, lists, xpacked);
  conv_all_kernel<<<648, 256, 0, stream>>>(Wn1, WPh, Wg_shared, WG1,
                                           Wg_head, WG2, Wn2, W2T);
  node_mfma_kernel<<<B_BR * 512, 512, 0, stream>>>(
      xpacked, WPh, bn1, W2T, bn2, cnt, pbase, lists, out);
  gemm_g1_kernel<<<B_BR * 64 * 4, 64, 0, stream>>>(xgb, WG1, bg_shared,
                                                   gcnt, glist, hgb);
  gemm_g2_kernel<<<B_BR * 64 * 2, 64, 0, stream>>>(hgb, WG2, bg_head,
                                                   gcnt, glist, out);
}

// Round 9
// 120.583 us; speedup vs baseline: 7.2492x; 1.6076x over previous
//
#include <hip/hip_runtime.h>

#define N_NODES 32768
#define G_GRAPHS 1024
#define D_DIM 512
#define H_DIM 768
#define B_BR 4
#define GHD 64
#define NHD 3

// output layout (f32, concatenated flat)
#define NH_OFF (G_GRAPHS * GHD)
#define GV_OFF (G_GRAPHS * GHD + N_NODES * NHD)
#define NV_OFF (2 * G_GRAPHS * GHD + N_NODES * NHD)

typedef unsigned short ushort_t;
typedef __attribute__((ext_vector_type(8))) short short8;
typedef __attribute__((ext_vector_type(4))) float f32x4;
typedef __attribute__((ext_vector_type(4))) ushort_t ushort4_t;

__device__ __forceinline__ ushort_t rne_bf16(float v) {
  unsigned bits = __float_as_uint(v);
  return (ushort_t)((bits + 0x7fffu + ((bits >> 16) & 1u)) >> 16);
}

// ---------------------------------------------------------------------------
// fused segment-bounds + 4-wave branch scan. One block, 1024 threads.
// ---------------------------------------------------------------------------
__global__ __launch_bounds__(1024) void segscan_kernel(
    const int* __restrict__ batch, const int* __restrict__ dsname,
    int* __restrict__ gstart, int* __restrict__ goff, int* __restrict__ glist,
    int* __restrict__ cnt, int* __restrict__ gcnt, int* __restrict__ pbase) {
  __shared__ int sg[G_GRAPHS + 1];
  __shared__ int scnt[4], sgcnt[4];
  const int tid = threadIdx.x;
  {
    int g = tid;
    int lo = 0, hi = N_NODES;
    while (lo < hi) { int mid = (lo + hi) >> 1; if (batch[mid] < g) lo = mid + 1; else hi = mid; }
    sg[g] = lo; gstart[g] = lo;
    if (tid == 0) { sg[G_GRAPHS] = N_NODES; gstart[G_GRAPHS] = N_NODES; }
  }
  __syncthreads();
  if (tid < 256) {
    const int lane = tid & 63;
    const int b = tid >> 6;
    int run_n = 0, run_g = 0;
    for (int c = 0; c < G_GRAPHS / 64; ++c) {
      int g = c * 64 + lane;
      int mine = (dsname[g] == b) ? 1 : 0;
      int len = mine ? (sg[g + 1] - sg[g]) : 0;
      int sl = len, so = mine;
#pragma unroll
      for (int off = 1; off < 64; off <<= 1) {
        int tl = __shfl_up(sl, off);
        int to = __shfl_up(so, off);
        if (lane >= off) { sl += tl; so += to; }
      }
      if (mine) {
        goff[g] = run_n + sl - len;
        glist[b * G_GRAPHS + run_g + so - 1] = g;
      }
      run_n += __shfl(sl, 63);
      run_g += __shfl(so, 63);
    }
    if (lane == 0) { scnt[b] = run_n; sgcnt[b] = run_g; }
  }
  __syncthreads();
  if (tid == 0) {
    int p = 0;
    for (int b2 = 0; b2 < 4; ++b2) {
      cnt[b2] = scnt[b2];
      gcnt[b2] = sgcnt[b2];
      pbase[b2] = p;
      p += (scnt[b2] + 63) & ~63;
    }
  }
}

// ---------------------------------------------------------------------------
// prep kernel: pool (bid<512) + pack_x (512..1023) + weight conv (1024..1671)
// ---------------------------------------------------------------------------
__global__ __launch_bounds__(256) void prep_kernel(
    const float* __restrict__ x, const int* __restrict__ batch,
    const int* __restrict__ dsname, const int* __restrict__ gstart,
    const int* __restrict__ goff, const int* __restrict__ pbase,
    int* __restrict__ lists, ushort_t* __restrict__ xp,
    ushort_t* __restrict__ xgb,
    const float* __restrict__ Wn1, ushort_t* __restrict__ WPh,
    const float* __restrict__ Wg1, ushort_t* __restrict__ WG1,
    const float* __restrict__ Wgh, ushort_t* __restrict__ WG2,
    const float* __restrict__ Wn2, ushort_t* __restrict__ W2T) {
  __shared__ float Ws[64][65];
  const int bid = blockIdx.x;
  const int tid = threadIdx.x;

  if (bid < 512) {
    // pool: 2 graphs per block, 128 threads each
    const int g = bid * 2 + (tid >> 7);
    const int tg = tid & 127;
    const int start = gstart[g], end = gstart[g + 1];
    const float inv = (end > start) ? 1.0f / (float)(end - start) : 0.0f;
    float4 acc = make_float4(0.f, 0.f, 0.f, 0.f);
    for (int i = start; i < end; ++i) {
      float4 v = *reinterpret_cast<const float4*>(&x[(size_t)i * D_DIM + tg * 4]);
      acc.x += v.x; acc.y += v.y; acc.z += v.z; acc.w += v.w;
    }
    ushort4_t h4;
    h4[0] = rne_bf16(acc.x * inv); h4[1] = rne_bf16(acc.y * inv);
    h4[2] = rne_bf16(acc.z * inv); h4[3] = rne_bf16(acc.w * inv);
    *reinterpret_cast<ushort4_t*>(&xgb[(size_t)g * D_DIM + tg * 4]) = h4;
  } else if (bid < 1024) {
    // pack x: 64 nodes per block, linear node walk, baked XOR swizzle
    const int blk = bid - 512;
#pragma unroll
    for (int it = 0; it < 16; ++it) {
      int u = it * 256 + tid;          // 64 nodes x 64 chunks
      int r = u >> 6, cp = u & 63;
      int n = blk * 64 + r;
      int g = batch[n];
      int b = dsname[g];
      int i = goff[g] + (n - gstart[g]);
      if (cp == 0) lists[b * N_NODES + i] = n;
      int dest = pbase[b] + i;
      int g8 = cp ^ (i & 7);
      const float* sp = x + (size_t)n * D_DIM + g8 * 8;
      float4 v0 = *reinterpret_cast<const float4*>(sp);
      float4 v1 = *reinterpret_cast<const float4*>(sp + 4);
      short8 h;
      h[0] = (short)rne_bf16(v0.x); h[1] = (short)rne_bf16(v0.y);
      h[2] = (short)rne_bf16(v0.z); h[3] = (short)rne_bf16(v0.w);
      h[4] = (short)rne_bf16(v1.x); h[5] = (short)rne_bf16(v1.y);
      h[6] = (short)rne_bf16(v1.z); h[7] = (short)rne_bf16(v1.w);
      *reinterpret_cast<short8*>(xp + (size_t)dest * 512 + cp * 8) = h;
    }
  } else {
    const int cid = bid - 1024;
    if (cid < 256) {  // Wn1 -> WPh
      int b = cid >> 6, t = cid & 63;
      int kt = t >> 3, nt = t & 7;
      const float* W = Wn1 + (size_t)b * D_DIM * D_DIM;
      for (int i = tid; i < 64 * 64; i += 256) {
        int k = i >> 6, n = i & 63;
        Ws[k][n] = W[(size_t)(kt * 64 + k) * D_DIM + nt * 64 + n];
      }
      __syncthreads();
      for (int i = tid; i < 64 * 8; i += 256) {
        int n = i >> 3, kq8 = i & 7;
        short8 sh;
#pragma unroll
        for (int j = 0; j < 8; ++j) sh[j] = (short)rne_bf16(Ws[kq8 * 8 + j][n]);
        int gn = nt * 64 + n, gk0 = kt * 64 + kq8 * 8;
        int n16 = gn >> 4, l15 = gn & 15;
        int ks = gk0 >> 5, lq = (gk0 >> 3) & 3;
        size_t off = ((((size_t)b * 32 + n16) * 16 + ks) * 64 + lq * 16 + l15) * 8;
        *reinterpret_cast<short8*>(WPh + off) = sh;
      }
    } else if (cid < 640) {  // Wg_shared -> WG1
      int l2 = cid - 256;
      int b = l2 / 96, t = l2 % 96;
      int kt = t / 12, nt = t % 12;
      const float* W = Wg1 + (size_t)b * D_DIM * H_DIM;
      for (int i = tid; i < 64 * 64; i += 256) {
        int k = i >> 6, n = i & 63;
        Ws[k][n] = W[(size_t)(kt * 64 + k) * H_DIM + nt * 64 + n];
      }
      __syncthreads();
      for (int i = tid; i < 64 * 8; i += 256) {
        int n = i >> 3, kq8 = i & 7;
        short8 sh;
#pragma unroll
        for (int j = 0; j < 8; ++j) sh[j] = (short)rne_bf16(Ws[kq8 * 8 + j][n]);
        int gn = nt * 64 + n, gk0 = kt * 64 + kq8 * 8;
        int n16 = gn >> 4, l15 = gn & 15;
        int ks = gk0 >> 5, lq = (gk0 >> 3) & 3;
        size_t off = ((((size_t)b * 48 + n16) * 16 + ks) * 64 + lq * 16 + l15) * 8;
        *reinterpret_cast<short8*>(WG1 + off) = sh;
      }
    } else if (cid < 644) {  // Wg_head -> WG2
      int b = cid - 640;
      const float* W = Wgh + (size_t)b * H_DIM * 2 * GHD;
      for (int i = tid; i < 8 * 24 * 64; i += 256) {
        int n16 = i / (24 * 64);
        int rem = i % (24 * 64);
        int ks = rem / 64, lane = rem % 64;
        int l15 = lane & 15, lq = lane >> 4;
        int o = n16 * 16 + l15;
        short8 sv;
#pragma unroll
        for (int j = 0; j < 8; ++j) {
          int k = ks * 32 + lq * 8 + j;
          sv[j] = (short)rne_bf16(W[(size_t)k * 128 + o]);
        }
        *reinterpret_cast<short8*>(WG2 + (size_t)i * 8 + (size_t)b * (8 * 24 * 64 * 8)) = sv;
      }
    } else {  // Wn2 -> W2T
      int b = cid - 644;
      for (int i = tid; i < 16 * D_DIM; i += 256) {
        int o = i & 15, c = i >> 4;
        float v = (o < 6) ? Wn2[(size_t)b * D_DIM * 6 + c * 6 + o] : 0.0f;
        W2T[(size_t)b * 16 * D_DIM + o * D_DIM + c] = rne_bf16(v);
      }
    }
  }
}

// ---------------------------------------------------------------------------
// mega kernel: blocks [0,2048) = node GEMM (8 waves, 64 rows x 512 cols),
// blocks [2048,2176) = graph MLP (8 waves, 32 graphs, L1+L2 fused).
// Graph blocks ride in the node blocks' occupancy shadow.
// ---------------------------------------------------------------------------
#define NBM 64
#define NODE_BLOCKS (B_BR * 512)

__global__ __launch_bounds__(512, 4) void mega_kernel(
    const ushort_t* __restrict__ xpacked,
    const ushort_t* __restrict__ WPh,
    const float* __restrict__ bn1,
    const ushort_t* __restrict__ W2T, const float* __restrict__ bn2,
    const int* __restrict__ cnt, const int* __restrict__ pbase,
    const int* __restrict__ lists,
    const ushort_t* __restrict__ xgb,
    const ushort_t* __restrict__ WG1, const float* __restrict__ bg_shared,
    const ushort_t* __restrict__ WG2, const float* __restrict__ bg_head,
    const int* __restrict__ gcnt, const int* __restrict__ glist,
    float* __restrict__ out) {
  __shared__ __align__(16) char smem[65536];
  __shared__ int idxbuf[64];

  const int bid = blockIdx.x;
  const int tid = threadIdx.x;
  const int lane = tid & 63;
  const int w = tid >> 6;
  const int l15 = lane & 15;
  const int lq = lane >> 4;

  if (bid < NODE_BLOCKS) {
    // ---------------- node path ----------------
    ushort_t* Ah = (ushort_t*)smem;
    const int b = bid >> 9;
    const int tile = bid & 511;
    const int count = cnt[b];
    const int base = tile * NBM;
    if (base >= count) return;
    const int pb = pbase[b];

    if (tid < NBM) {
      int r = base + tid;
      idxbuf[tid] = (r < count) ? lists[b * N_NODES + r] : lists[b * N_NODES];
    }

    const char* srow = (const char*)(xpacked + (size_t)(pb + base) * 512);
#pragma unroll
    for (int i = 0; i < 8; ++i) {
      int row = w * 8 + i;
      const void* gsrc = srow + (size_t)row * 1024 + (size_t)lane * 16;
      __builtin_amdgcn_global_load_lds(
          (const __attribute__((address_space(1))) void*)gsrc,
          (__attribute__((address_space(3))) void*)((char*)Ah + row * 1024),
          16, 0, 0);
    }
    __syncthreads();

    f32x4 acc[4][4];
#pragma unroll
    for (int i = 0; i < 4; ++i)
#pragma unroll
      for (int j = 0; j < 4; ++j) acc[i][j] = (f32x4){0.f, 0.f, 0.f, 0.f};

    const ushort_t* __restrict__ wph =
        WPh + (((size_t)b * 32 + w * 4) * 16) * 512 + (size_t)lane * 8;

    for (int ks = 0; ks < 16; ++ks) {
      short8 ah[4];
#pragma unroll
      for (int rt = 0; rt < 4; ++rt) {
        int R = rt * 16 + l15;
        int byteoff = R * 1024 + ((ks * 64 + lq * 16) ^ ((R & 7) << 4));
        ah[rt] = *reinterpret_cast<const short8*>((const char*)Ah + byteoff);
      }
#pragma unroll
      for (int ct = 0; ct < 4; ++ct) {
        short8 bh = *reinterpret_cast<const short8*>(wph + (size_t)(ct * 16 + ks) * 512);
#pragma unroll
        for (int rt = 0; rt < 4; ++rt) {
          acc[rt][ct] = __builtin_amdgcn_mfma_f32_16x16x32_bf16(ah[rt], bh, acc[rt][ct], 0, 0, 0);
        }
      }
    }

    __syncthreads();
    ushort_t* hn = Ah;
#pragma unroll
    for (int ct = 0; ct < 4; ++ct) {
      int n = w * 64 + ct * 16 + l15;
      float bias = bn1[b * D_DIM + n];
#pragma unroll
      for (int rt = 0; rt < 4; ++rt) {
#pragma unroll
        for (int j = 0; j < 4; ++j) {
          int row = rt * 16 + lq * 4 + j;
          float v = fmaxf(acc[rt][ct][j] + bias, 0.0f);
          int byteoff = row * 1024 + ((n * 2) ^ ((row & 7) << 4));
          *reinterpret_cast<ushort_t*>((char*)hn + byteoff) = rne_bf16(v);
        }
      }
    }
    __syncthreads();

    if (w < 4) {
      f32x4 acc2 = (f32x4){0.f, 0.f, 0.f, 0.f};
      const ushort_t* __restrict__ w2 =
          W2T + (size_t)b * (16 * 512) + (size_t)l15 * 512 + lq * 8;
      const int R = w * 16 + l15;
#pragma unroll
      for (int ks = 0; ks < 16; ++ks) {
        int byteoff = R * 1024 + ((ks * 64 + lq * 16) ^ ((R & 7) << 4));
        short8 a2 = *reinterpret_cast<const short8*>((const char*)hn + byteoff);
        short8 b2 = *reinterpret_cast<const short8*>(w2 + ks * 32);
        acc2 = __builtin_amdgcn_mfma_f32_16x16x32_bf16(a2, b2, acc2, 0, 0, 0);
      }
      int o = l15;
      if (o < 6) {
        float bo = bn2[b * 6 + o];
#pragma unroll
        for (int j = 0; j < 4; ++j) {
          int r = w * 16 + lq * 4 + j;
          if (base + r < count) {
            int n = idxbuf[r];
            float v = acc2[j] + bo;
            if (o < NHD) out[NH_OFF + n * NHD + o] = v;
            else out[NV_OFF + n * NHD + (o - NHD)] = v * v;
          }
        }
      }
    }
  } else {
    // ---------------- graph path ----------------
    const int gb = bid - NODE_BLOCKS;
    const int b = gb >> 5;
    const int tile = gb & 31;
    const int gc = gcnt[b];
    const int base = tile * 32;
    if (base >= gc) return;

    ushort_t* Ag = (ushort_t*)smem;       // 32 x 512 bf16, swizzled (32 KB)
    if (tid < 32) {
      int r = base + tid;
      idxbuf[tid] = (r < gc) ? glist[b * G_GRAPHS + r] : glist[b * G_GRAPHS];
    }
    __syncthreads();

    // stage xgb rows: 32 rows x 64 chunks(16B) = 2048 units, 4 iters
#pragma unroll
    for (int it = 0; it < 4; ++it) {
      int u = it * 512 + tid;
      int r = u >> 6, cp = u & 63;
      const ushort_t* sp = xgb + (size_t)idxbuf[r] * D_DIM + cp * 8;
      short8 h = *reinterpret_cast<const short8*>(sp);
      int byteoff = r * 1024 + ((cp * 16) ^ ((r & 7) << 4));
      *reinterpret_cast<short8*>((char*)Ag + byteoff) = h;
    }
    __syncthreads();

    // L1: wave w -> cols [w*96, w*96+96) = 6 col tiles; 2 row tiles
    f32x4 acc[2][6];
#pragma unroll
    for (int i = 0; i < 2; ++i)
#pragma unroll
      for (int j = 0; j < 6; ++j) acc[i][j] = (f32x4){0.f, 0.f, 0.f, 0.f};

    const ushort_t* __restrict__ g1 =
        WG1 + (((size_t)b * 48 + w * 6) * 16) * 512 + (size_t)lane * 8;

    for (int ks = 0; ks < 16; ++ks) {
      short8 ah[2];
#pragma unroll
      for (int rt = 0; rt < 2; ++rt) {
        int R = rt * 16 + l15;
        int byteoff = R * 1024 + ((ks * 64 + lq * 16) ^ ((R & 7) << 4));
        ah[rt] = *reinterpret_cast<const short8*>((const char*)Ag + byteoff);
      }
#pragma unroll
      for (int ct = 0; ct < 6; ++ct) {
        short8 bh = *reinterpret_cast<const short8*>(g1 + (size_t)(ct * 16 + ks) * 512);
#pragma unroll
        for (int rt = 0; rt < 2; ++rt) {
          acc[rt][ct] = __builtin_amdgcn_mfma_f32_16x16x32_bf16(ah[rt], bh, acc[rt][ct], 0, 0, 0);
        }
      }
    }

    __syncthreads();  // done reading Ag; reuse smem as hg (32 x 768 bf16, stride 1536B)
    ushort_t* hgs = (ushort_t*)smem;
#pragma unroll
    for (int ct = 0; ct < 6; ++ct) {
      int n = w * 96 + ct * 16 + l15;
      float bias = bg_shared[b * H_DIM + n];
#pragma unroll
      for (int rt = 0; rt < 2; ++rt) {
#pragma unroll
        for (int j = 0; j < 4; ++j) {
          int row = rt * 16 + lq * 4 + j;
          float v = fmaxf(acc[rt][ct][j] + bias, 0.0f);
          int byteoff = row * 1536 + ((n * 2) ^ ((row & 7) << 4));
          *reinterpret_cast<ushort_t*>((char*)hgs + byteoff) = rne_bf16(v);
        }
      }
    }
    __syncthreads();

    // L2: wave w -> o-tile w (16 cols); 2 row tiles; K=768
    f32x4 acc2[2];
    acc2[0] = (f32x4){0.f, 0.f, 0.f, 0.f};
    acc2[1] = (f32x4){0.f, 0.f, 0.f, 0.f};
    const ushort_t* __restrict__ g2 =
        WG2 + ((size_t)(b * 8 + w) * 24 * 64 + lane) * 8;

    for (int ks = 0; ks < 24; ++ks) {
      short8 b2 = *reinterpret_cast<const short8*>(g2 + (size_t)ks * 512);
#pragma unroll
      for (int rt = 0; rt < 2; ++rt) {
        int R = rt * 16 + l15;
        int byteoff = R * 1536 + ((ks * 64 + lq * 16) ^ ((R & 7) << 4));
        short8 a2 = *reinterpret_cast<const short8*>((const char*)hgs + byteoff);
        acc2[rt] = __builtin_amdgcn_mfma_f32_16x16x32_bf16(a2, b2, acc2[rt], 0, 0, 0);
      }
    }

    int o = w * 16 + l15;
    float bo = bg_head[b * 2 * GHD + o];
#pragma unroll
    for (int rt = 0; rt < 2; ++rt) {
#pragma unroll
      for (int j = 0; j < 4; ++j) {
        int r = rt * 16 + lq * 4 + j;
        if (base + r < gc) {
          int g = idxbuf[r];
          float v = acc2[rt][j] + bo;
          if (o < GHD) out[g * GHD + o] = v;
          else out[GV_OFF + g * GHD + (o - GHD)] = v * v;
        }
      }
    }
  }
}

// ---------------------------------------------------------------------------
extern "C" void kernel_launch(void* const* d_in, const int* in_sizes, int n_in,
                              void* d_out, int out_size, void* d_ws, size_t ws_size,
                              hipStream_t stream) {
  const float* x         = (const float*)d_in[0];
  const int*   batch     = (const int*)d_in[1];
  const int*   dsname    = (const int*)d_in[2];
  const float* Wg_shared = (const float*)d_in[3];
  const float* bg_shared = (const float*)d_in[4];
  const float* Wg_head   = (const float*)d_in[5];
  const float* bg_head   = (const float*)d_in[6];
  const float* Wn1       = (const float*)d_in[7];
  const float* bn1       = (const float*)d_in[8];
  const float* Wn2       = (const float*)d_in[9];
  const float* bn2       = (const float*)d_in[10];
  float* out = (float*)d_out;

  int* ws_i   = (int*)d_ws;
  int* cnt    = ws_i;               // 4
  int* gcnt   = ws_i + 8;           // 4
  int* pbase  = ws_i + 12;          // 4
  int* gstart = ws_i + 16;          // 1025
  int* goff   = ws_i + 1056;        // 1024
  int* glist  = ws_i + 2080;        // 4096
  int* lists  = ws_i + 6176;        // 4*32768 -> end 137248
  ushort_t* xgb  = (ushort_t*)(ws_i + 137248);  // 1024*512
  ushort_t* WPh  = xgb + 524288;                // 4*512*512
  ushort_t* W2T  = WPh + 1048576;               // 4*16*512
  ushort_t* WG1  = W2T + 32768;                 // 1572864
  ushort_t* WG2  = WG1 + 1572864;               // 393216
  ushort_t* xpacked = WG2 + 393216;             // 33024 rows * 512

  segscan_kernel<<<1, 1024, 0, stream>>>(batch, dsname, gstart, goff, glist,
                                         cnt, gcnt, pbase);
  prep_kernel<<<1672, 256, 0, stream>>>(x, batch, dsname, gstart, goff, pbase,
                                        lists, xpacked, xgb,
                                        Wn1, WPh, Wg_shared, WG1,
                                        Wg_head, WG2, Wn2, W2T);
  mega_kernel<<<NODE_BLOCKS + 128, 512, 0, stream>>>(
      xpacked, WPh, bn1, W2T, bn2, cnt, pbase, lists,
      xgb, WG1, bg_shared, WG2, bg_head, gcnt, glist, out);
}